// Round 1
// baseline (9225.585 us; speedup 1.0000x reference)
//
#include <hip/hip_runtime.h>
#include <math.h>
#include <stdint.h>

// Problem constants (match reference)
#define Bb 2
#define Lq 2048
#define Dm 2048
#define Hh 16
#define DH 128
#define DREL 64
#define KTOP 512   // 0.25 * L

#define NEG_INF (-__builtin_huge_valf())

// ---------------------------------------------------------------------------
// Tiled fp32 GEMM: C[M,N] = A[M,K] @ W[N,K]^T   (nn.Linear semantics)
// BM=BN=128, BK=16, 256 threads, 8x8 micro-tile per thread.
// ---------------------------------------------------------------------------
#define BM 128
#define BN 128
#define BK 16
#define TM 8
#define TN 8

__global__ __launch_bounds__(256) void gemm_nt(const float* __restrict__ A,
                                               const float* __restrict__ W,
                                               float* __restrict__ C,
                                               int M, int N, int Kd) {
  __shared__ float As[BK][BM];
  __shared__ float Bs[BK][BN];
  const int tid = threadIdx.x;
  const int m0 = blockIdx.y * BM;
  const int n0 = blockIdx.x * BN;
  const int tx = tid & 15;        // 0..15 -> col groups of 8
  const int ty = tid >> 4;        // 0..15 -> row groups of 8
  const int lr = tid >> 1;        // 0..127 loader row
  const int lk = (tid & 1) * 8;   // 0 or 8

  float acc[TM][TN];
#pragma unroll
  for (int i = 0; i < TM; ++i)
#pragma unroll
    for (int j = 0; j < TN; ++j) acc[i][j] = 0.0f;

  for (int k0 = 0; k0 < Kd; k0 += BK) {
    // --- load A tile (rows m0+lr) ---
    {
      const int gm = m0 + lr;
      float4 a0 = make_float4(0, 0, 0, 0), a1 = a0;
      if (gm < M) {
        const float* ap = A + (size_t)gm * Kd + k0 + lk;
        a0 = *(const float4*)(ap);
        a1 = *(const float4*)(ap + 4);
      }
      As[lk + 0][lr] = a0.x; As[lk + 1][lr] = a0.y;
      As[lk + 2][lr] = a0.z; As[lk + 3][lr] = a0.w;
      As[lk + 4][lr] = a1.x; As[lk + 5][lr] = a1.y;
      As[lk + 6][lr] = a1.z; As[lk + 7][lr] = a1.w;
    }
    // --- load B tile (rows n0+lr of W) ---
    {
      const int gn = n0 + lr;
      float4 b0 = make_float4(0, 0, 0, 0), b1 = b0;
      if (gn < N) {
        const float* bp = W + (size_t)gn * Kd + k0 + lk;
        b0 = *(const float4*)(bp);
        b1 = *(const float4*)(bp + 4);
      }
      Bs[lk + 0][lr] = b0.x; Bs[lk + 1][lr] = b0.y;
      Bs[lk + 2][lr] = b0.z; Bs[lk + 3][lr] = b0.w;
      Bs[lk + 4][lr] = b1.x; Bs[lk + 5][lr] = b1.y;
      Bs[lk + 6][lr] = b1.z; Bs[lk + 7][lr] = b1.w;
    }
    __syncthreads();

#pragma unroll
    for (int kk = 0; kk < BK; ++kk) {
      float af[TM], bf[TN];
#pragma unroll
      for (int i = 0; i < TM; ++i) af[i] = As[kk][ty * TM + i];
#pragma unroll
      for (int j = 0; j < TN; ++j) bf[j] = Bs[kk][tx * TN + j];
#pragma unroll
      for (int i = 0; i < TM; ++i)
#pragma unroll
        for (int j = 0; j < TN; ++j) acc[i][j] += af[i] * bf[j];
    }
    __syncthreads();
  }

  // --- store ---
  const int gn = n0 + tx * TN;
  if (gn < N) {  // N is a multiple of 8 here (64 or 2048), so full 8-wide rows
#pragma unroll
    for (int i = 0; i < TM; ++i) {
      const int gm = m0 + ty * TM + i;
      if (gm < M) {
        float4* cp = (float4*)(C + (size_t)gm * N + gn);
        cp[0] = make_float4(acc[i][0], acc[i][1], acc[i][2], acc[i][3]);
        cp[1] = make_float4(acc[i][4], acc[i][5], acc[i][6], acc[i][7]);
      }
    }
  }
}

// ---------------------------------------------------------------------------
// Per-(b,q) rel-score + exact top-K (radix select on fp32 total order) -> bitmask
// One block per query row; 256 threads.
// Mask bit j set iff: j<=q && ( (q+1)<=K  ||  key[j] >= kth_key  ||  j==q )
// ---------------------------------------------------------------------------
__global__ __launch_bounds__(256) void relmask_kernel(const float* __restrict__ qrel,
                                                      const float* __restrict__ krel,
                                                      uint32_t* __restrict__ mask) {
  const int bid = blockIdx.x;
  const int qi = bid % Lq;
  const int b = bid / Lq;
  const int tid = threadIdx.x;

  __shared__ float qv[DREL];
  __shared__ uint32_t keys[Lq];
  __shared__ uint32_t prefix_s;
  __shared__ int r_s;
  __shared__ int cnt_s;

  if (tid < DREL) qv[tid] = qrel[((size_t)(b * Lq + qi)) * DREL + tid];
  __syncthreads();

  const int n = qi + 1;

  for (int j = tid; j < Lq; j += 256) {
    uint32_t key = 0u;
    if (j < n) {
      const float4* kp = (const float4*)(krel + ((size_t)(b * Lq + j)) * DREL);
      float acc = 0.0f;
#pragma unroll
      for (int t = 0; t < DREL / 4; ++t) {
        float4 k4 = kp[t];
        acc += qv[4 * t + 0] * k4.x + qv[4 * t + 1] * k4.y +
               qv[4 * t + 2] * k4.z + qv[4 * t + 3] * k4.w;
      }
      const float s = acc * 0.125f;  // DREL^-0.5
      uint32_t u = __float_as_uint(s);
      key = (u & 0x80000000u) ? ~u : (u | 0x80000000u);  // monotone total order
    }
    keys[j] = key;
  }

  uint32_t kth = 0u;
  if (n > KTOP) {
    if (tid == 0) { prefix_s = 0u; r_s = KTOP; }
    __syncthreads();
    for (int bit = 31; bit >= 0; --bit) {
      const uint32_t cand_hi = (prefix_s >> bit) | 1u;
      int local = 0;
      for (int j = tid; j < n; j += 256)
        if ((keys[j] >> bit) == cand_hi) local++;
      if (tid == 0) cnt_s = 0;
      __syncthreads();
      if (local) atomicAdd(&cnt_s, local);
      __syncthreads();
      if (tid == 0) {
        if (cnt_s >= r_s) prefix_s |= (1u << bit);
        else r_s -= cnt_s;
      }
      __syncthreads();
    }
    kth = prefix_s;
  }
  __syncthreads();

  for (int w = tid; w < Lq / 32; w += 256) {
    uint32_t word = 0u;
#pragma unroll
    for (int i = 0; i < 32; ++i) {
      const int j = w * 32 + i;
      const bool ok = (j < n) && ((n <= KTOP) || (keys[j] >= kth) || (j == qi));
      if (ok) word |= (1u << i);
    }
    mask[((size_t)(b * Lq + qi)) * (Lq / 32) + w] = word;
  }
}

// ---------------------------------------------------------------------------
// Sparse masked attention, one block per (b, h, q). fp32, two-pass softmax
// with scores staged in LDS; masked keys skipped entirely.
// ---------------------------------------------------------------------------
__global__ __launch_bounds__(256) void attn_sparse(const float* __restrict__ qb,
                                                   const float* __restrict__ kb,
                                                   const float* __restrict__ vb,
                                                   const uint32_t* __restrict__ mask,
                                                   float* __restrict__ ctx) {
  const int bid = blockIdx.x;
  const int qi = bid % Lq;
  const int h = (bid / Lq) % Hh;
  const int b = bid / (Lq * Hh);
  const int tid = threadIdx.x;

  __shared__ float p[Lq];
  __shared__ float qv[DH];
  __shared__ float red[256];
  __shared__ float part[2][DH];

  const size_t rowQ = ((size_t)(b * Lq + qi)) * Dm + h * DH;
  if (tid < DH) qv[tid] = qb[rowQ + tid];
  __syncthreads();

  const int n = qi + 1;
  const uint32_t* mrow = mask + ((size_t)(b * Lq + qi)) * (Lq / 32);
  const float scale = 0.08838834764831845f;  // 1/sqrt(128)

  float lmax = NEG_INF;
  for (int j = tid; j < n; j += 256) {
    float s = NEG_INF;
    if ((mrow[j >> 5] >> (j & 31)) & 1u) {
      const float4* kp = (const float4*)(kb + ((size_t)(b * Lq + j)) * Dm + h * DH);
      float acc = 0.0f;
#pragma unroll
      for (int t = 0; t < DH / 4; ++t) {
        float4 k4 = kp[t];
        acc += qv[4 * t + 0] * k4.x + qv[4 * t + 1] * k4.y +
               qv[4 * t + 2] * k4.z + qv[4 * t + 3] * k4.w;
      }
      s = acc * scale;
    }
    p[j] = s;
    lmax = fmaxf(lmax, s);
  }
  red[tid] = lmax;
  __syncthreads();
  for (int o = 128; o > 0; o >>= 1) {
    if (tid < o) red[tid] = fmaxf(red[tid], red[tid + o]);
    __syncthreads();
  }
  const float m = red[0];
  __syncthreads();

  float lsum = 0.0f;
  for (int j = tid; j < n; j += 256) {
    const float s = p[j];
    const float e = (s == NEG_INF) ? 0.0f : expf(s - m);
    p[j] = e;
    lsum += e;
  }
  red[tid] = lsum;
  __syncthreads();
  for (int o = 128; o > 0; o >>= 1) {
    if (tid < o) red[tid] += red[tid + o];
    __syncthreads();
  }
  const float l = red[0];
  __syncthreads();

  // PV: 2 halves x 128 d-lanes; p[j] is wave-uniform -> skip is uniform.
  const int d = tid & 127;
  const int half = tid >> 7;
  float acc = 0.0f;
  for (int j = half; j < n; j += 2) {
    const float pj = p[j];
    if (pj != 0.0f) acc += pj * vb[((size_t)(b * Lq + j)) * Dm + h * DH + d];
  }
  part[half][d] = acc;
  __syncthreads();
  if (tid < DH) ctx[rowQ + tid] = (part[0][tid] + part[1][tid]) / l;
}

// ---------------------------------------------------------------------------
extern "C" void kernel_launch(void* const* d_in, const int* in_sizes, int n_in,
                              void* d_out, int out_size, void* d_ws, size_t ws_size,
                              hipStream_t stream) {
  const float* hs  = (const float*)d_in[0];
  const float* rel = (const float*)d_in[1];
  const float* Wqr = (const float*)d_in[2];
  const float* Wkr = (const float*)d_in[3];
  const float* Wq  = (const float*)d_in[4];
  const float* Wk  = (const float*)d_in[5];
  const float* Wv  = (const float*)d_in[6];
  const float* Wo  = (const float*)d_in[7];
  float* out = (float*)d_out;

  float* ws = (float*)d_ws;
  const int M = Bb * Lq;  // 4096
  size_t off = 0;
  float* qrel = ws + off; off += (size_t)M * DREL;
  float* krel = ws + off; off += (size_t)M * DREL;
  float* qb   = ws + off; off += (size_t)M * Dm;
  float* kb   = ws + off; off += (size_t)M * Dm;
  float* vb   = ws + off; off += (size_t)M * Dm;
  float* ctx  = ws + off; off += (size_t)M * Dm;
  uint32_t* maskb = (uint32_t*)(ws + off);  // M * 64 words = 1 MB

  const dim3 blk(256);

  // rel projections: [4096,64] = rel @ W_*_rel^T
  gemm_nt<<<dim3(1, M / BM), blk, 0, stream>>>(rel, Wqr, qrel, M, DREL, Dm);
  gemm_nt<<<dim3(1, M / BM), blk, 0, stream>>>(rel, Wkr, krel, M, DREL, Dm);

  // QKV projections: [4096,2048]
  gemm_nt<<<dim3(Dm / BN, M / BM), blk, 0, stream>>>(hs, Wq, qb, M, Dm, Dm);
  gemm_nt<<<dim3(Dm / BN, M / BM), blk, 0, stream>>>(hs, Wk, kb, M, Dm, Dm);
  gemm_nt<<<dim3(Dm / BN, M / BM), blk, 0, stream>>>(hs, Wv, vb, M, Dm, Dm);

  // top-K mask per query row
  relmask_kernel<<<M, blk, 0, stream>>>(qrel, krel, maskb);

  // sparse attention -> ctx
  attn_sparse<<<Bb * Hh * Lq, blk, 0, stream>>>(qb, kb, vb, maskb, ctx);

  // output projection -> d_out
  gemm_nt<<<dim3(Dm / BN, M / BM), blk, 0, stream>>>(ctx, Wo, out, M, Dm, Dm);
}

// Round 2
// 2938.466 us; speedup vs baseline: 3.1396x; 3.1396x over previous
//
#include <hip/hip_runtime.h>
#include <math.h>
#include <stdint.h>

// Problem constants (match reference)
#define Bb 2
#define Lq 2048
#define Dm 2048
#define Hh 16
#define DH 128
#define DREL 64
#define KTOP 512   // 0.25 * L

#define NEG_INF (-__builtin_huge_valf())

typedef __attribute__((ext_vector_type(8))) short bf16x8;   // 8 bf16 (4 VGPRs)
typedef __attribute__((ext_vector_type(4))) float f32x4;

static __device__ inline unsigned short f2bf(float f) {
  unsigned int u = __float_as_uint(f);
  u += 0x7fffu + ((u >> 16) & 1u);   // RNE
  return (unsigned short)(u >> 16);
}

// ---------------------------------------------------------------------------
// Tiled fp32 GEMM: C[M,N] = A[M,K] @ W[N,K]^T   (nn.Linear semantics)
// ---------------------------------------------------------------------------
#define BM 128
#define BN 128
#define BK 16
#define TM 8
#define TN 8

__global__ __launch_bounds__(256) void gemm_nt(const float* __restrict__ A,
                                               const float* __restrict__ W,
                                               float* __restrict__ C,
                                               int M, int N, int Kd) {
  __shared__ float As[BK][BM];
  __shared__ float Bs[BK][BN];
  const int tid = threadIdx.x;
  const int m0 = blockIdx.y * BM;
  const int n0 = blockIdx.x * BN;
  const int tx = tid & 15;
  const int ty = tid >> 4;
  const int lr = tid >> 1;
  const int lk = (tid & 1) * 8;

  float acc[TM][TN];
#pragma unroll
  for (int i = 0; i < TM; ++i)
#pragma unroll
    for (int j = 0; j < TN; ++j) acc[i][j] = 0.0f;

  for (int k0 = 0; k0 < Kd; k0 += BK) {
    {
      const int gm = m0 + lr;
      float4 a0 = make_float4(0, 0, 0, 0), a1 = a0;
      if (gm < M) {
        const float* ap = A + (size_t)gm * Kd + k0 + lk;
        a0 = *(const float4*)(ap);
        a1 = *(const float4*)(ap + 4);
      }
      As[lk + 0][lr] = a0.x; As[lk + 1][lr] = a0.y;
      As[lk + 2][lr] = a0.z; As[lk + 3][lr] = a0.w;
      As[lk + 4][lr] = a1.x; As[lk + 5][lr] = a1.y;
      As[lk + 6][lr] = a1.z; As[lk + 7][lr] = a1.w;
    }
    {
      const int gn = n0 + lr;
      float4 b0 = make_float4(0, 0, 0, 0), b1 = b0;
      if (gn < N) {
        const float* bp = W + (size_t)gn * Kd + k0 + lk;
        b0 = *(const float4*)(bp);
        b1 = *(const float4*)(bp + 4);
      }
      Bs[lk + 0][lr] = b0.x; Bs[lk + 1][lr] = b0.y;
      Bs[lk + 2][lr] = b0.z; Bs[lk + 3][lr] = b0.w;
      Bs[lk + 4][lr] = b1.x; Bs[lk + 5][lr] = b1.y;
      Bs[lk + 6][lr] = b1.z; Bs[lk + 7][lr] = b1.w;
    }
    __syncthreads();

#pragma unroll
    for (int kk = 0; kk < BK; ++kk) {
      float af[TM], bf[TN];
#pragma unroll
      for (int i = 0; i < TM; ++i) af[i] = As[kk][ty * TM + i];
#pragma unroll
      for (int j = 0; j < TN; ++j) bf[j] = Bs[kk][tx * TN + j];
#pragma unroll
      for (int i = 0; i < TM; ++i)
#pragma unroll
        for (int j = 0; j < TN; ++j) acc[i][j] += af[i] * bf[j];
    }
    __syncthreads();
  }

  const int gn = n0 + tx * TN;
  if (gn < N) {
#pragma unroll
    for (int i = 0; i < TM; ++i) {
      const int gm = m0 + ty * TM + i;
      if (gm < M) {
        float4* cp = (float4*)(C + (size_t)gm * N + gn);
        cp[0] = make_float4(acc[i][0], acc[i][1], acc[i][2], acc[i][3]);
        cp[1] = make_float4(acc[i][4], acc[i][5], acc[i][6], acc[i][7]);
      }
    }
  }
}

// ---------------------------------------------------------------------------
// Per-(b,q) rel-score + exact top-K (radix select, fp32 total order) -> bitmask
// Bit j of word w of row (b,q): key j=32w+i allowed (combined causal+sparse).
// ---------------------------------------------------------------------------
__global__ __launch_bounds__(256) void relmask_kernel(const float* __restrict__ qrel,
                                                      const float* __restrict__ krel,
                                                      uint32_t* __restrict__ mask) {
  const int bid = blockIdx.x;
  const int qi = bid % Lq;
  const int b = bid / Lq;
  const int tid = threadIdx.x;

  __shared__ float qv[DREL];
  __shared__ uint32_t keys[Lq];
  __shared__ uint32_t prefix_s;
  __shared__ int r_s;
  __shared__ int cnt_s;

  if (tid < DREL) qv[tid] = qrel[((size_t)(b * Lq + qi)) * DREL + tid];
  __syncthreads();

  const int n = qi + 1;

  for (int j = tid; j < Lq; j += 256) {
    uint32_t key = 0u;
    if (j < n) {
      const float4* kp = (const float4*)(krel + ((size_t)(b * Lq + j)) * DREL);
      float acc = 0.0f;
#pragma unroll
      for (int t = 0; t < DREL / 4; ++t) {
        float4 k4 = kp[t];
        acc += qv[4 * t + 0] * k4.x + qv[4 * t + 1] * k4.y +
               qv[4 * t + 2] * k4.z + qv[4 * t + 3] * k4.w;
      }
      const float s = acc * 0.125f;  // DREL^-0.5
      uint32_t u = __float_as_uint(s);
      key = (u & 0x80000000u) ? ~u : (u | 0x80000000u);
    }
    keys[j] = key;
  }

  uint32_t kth = 0u;
  if (n > KTOP) {
    if (tid == 0) { prefix_s = 0u; r_s = KTOP; }
    __syncthreads();
    for (int bit = 31; bit >= 0; --bit) {
      const uint32_t cand_hi = (prefix_s >> bit) | 1u;
      int local = 0;
      for (int j = tid; j < n; j += 256)
        if ((keys[j] >> bit) == cand_hi) local++;
      if (tid == 0) cnt_s = 0;
      __syncthreads();
      if (local) atomicAdd(&cnt_s, local);
      __syncthreads();
      if (tid == 0) {
        if (cnt_s >= r_s) prefix_s |= (1u << bit);
        else r_s -= cnt_s;
      }
      __syncthreads();
    }
    kth = prefix_s;
  }
  __syncthreads();

  for (int w = tid; w < Lq / 32; w += 256) {
    uint32_t word = 0u;
#pragma unroll
    for (int i = 0; i < 32; ++i) {
      const int j = w * 32 + i;
      const bool ok = (j < n) && ((n <= KTOP) || (keys[j] >= kth) || (j == qi));
      if (ok) word |= (1u << i);
    }
    mask[((size_t)(b * Lq + qi)) * (Lq / 32) + w] = word;
  }
}

// ---------------------------------------------------------------------------
// Dense flash attention with additive bitmask, bf16 MFMA (16x16x32).
// Block: 256 threads = 4 waves; each wave owns 16 q-rows -> TQ=64. TK=32.
// Layouts (verified, learn_hip m89/m91/m120):
//   A-frag:  A[m=lane&15][k=quad*8+j]
//   B-frag:  B[k=quad*8+j][n=lane&15]
//   C/D:     col=lane&15, row=quad*4+reg
// P (C-layout) -> A-layout via LDS round-trip. V staged transposed (Vt).
// ---------------------------------------------------------------------------
__global__ __launch_bounds__(256) void attn_flash(const float* __restrict__ qb,
                                                  const float* __restrict__ kb,
                                                  const float* __restrict__ vb,
                                                  const uint32_t* __restrict__ mask,
                                                  float* __restrict__ ctx) {
  __shared__ unsigned short Ks[32][136];   // [key][dim], 272B rows (16B-aligned)
  __shared__ unsigned short Vt[128][40];   // [dim][key], 80B rows (16B-aligned)
  __shared__ unsigned short Ps[4][16][40]; // per-wave P tile [m][key]
  __shared__ uint32_t mw[64];              // mask word per block q-row, this tile

  const int qt = (int)gridDim.x - 1 - (int)blockIdx.x;  // heavy blocks first
  const int h = blockIdx.y;
  const int b = blockIdx.z;
  const int tid = threadIdx.x;
  const int w = tid >> 6;          // wave 0..3
  const int lane = tid & 63;
  const int l15 = lane & 15;
  const int quad = lane >> 4;

  const int q0 = qt * 64;
  const float scale = 0.08838834764831845f;  // DH^-0.5
  const float L2E = 1.4426950408889634f;

  // --- load Q fragments (bf16) for this wave's 16 rows ---
  const int myq = q0 + w * 16 + l15;
  const float* qrow = qb + ((size_t)(b * Lq + myq)) * Dm + h * DH;
  bf16x8 aq[4];
#pragma unroll
  for (int kk = 0; kk < 4; ++kk) {
    const float* p = qrow + kk * 32 + quad * 8;
    float4 f0 = *(const float4*)(p);
    float4 f1 = *(const float4*)(p + 4);
    bf16x8 a;
    a[0] = (short)f2bf(f0.x); a[1] = (short)f2bf(f0.y);
    a[2] = (short)f2bf(f0.z); a[3] = (short)f2bf(f0.w);
    a[4] = (short)f2bf(f1.x); a[5] = (short)f2bf(f1.y);
    a[6] = (short)f2bf(f1.z); a[7] = (short)f2bf(f1.w);
    aq[kk] = a;
  }

  f32x4 O[8];
#pragma unroll
  for (int f = 0; f < 8; ++f) O[f] = (f32x4){0.f, 0.f, 0.f, 0.f};
  float m_[4] = {NEG_INF, NEG_INF, NEG_INF, NEG_INF};
  float l_[4] = {0.f, 0.f, 0.f, 0.f};

  const int nt = (q0 + 64) / 32;  // causal tile count

  // staging thread mapping
  const int skey = tid >> 3;          // 0..31 (K stage)
  const int scg = tid & 7;            // 0..7  -> dims scg*16..+16
  const int vkp = tid & 15;           // key pair (V stage)
  const int vdg = tid >> 4;           // 0..15 -> dims vdg*8..+8

  for (int kt = 0; kt < nt; ++kt) {
    const int kbase = kt * 32;
    // ---- stage K tile [32][128] bf16 ----
    {
      const float* kr = kb + ((size_t)(b * Lq + kbase + skey)) * Dm + h * DH + scg * 16;
      float4 f0 = *(const float4*)(kr + 0);
      float4 f1 = *(const float4*)(kr + 4);
      float4 f2 = *(const float4*)(kr + 8);
      float4 f3 = *(const float4*)(kr + 12);
      bf16x8 lo, hi;
      lo[0] = (short)f2bf(f0.x); lo[1] = (short)f2bf(f0.y);
      lo[2] = (short)f2bf(f0.z); lo[3] = (short)f2bf(f0.w);
      lo[4] = (short)f2bf(f1.x); lo[5] = (short)f2bf(f1.y);
      lo[6] = (short)f2bf(f1.z); lo[7] = (short)f2bf(f1.w);
      hi[0] = (short)f2bf(f2.x); hi[1] = (short)f2bf(f2.y);
      hi[2] = (short)f2bf(f2.z); hi[3] = (short)f2bf(f2.w);
      hi[4] = (short)f2bf(f3.x); hi[5] = (short)f2bf(f3.y);
      hi[6] = (short)f2bf(f3.z); hi[7] = (short)f2bf(f3.w);
      *(bf16x8*)&Ks[skey][scg * 16] = lo;
      *(bf16x8*)&Ks[skey][scg * 16 + 8] = hi;
    }
    // ---- stage V tile transposed Vt[128][32] bf16 (packed dword writes) ----
    {
      const float* va = vb + ((size_t)(b * Lq + kbase + 2 * vkp)) * Dm + h * DH + vdg * 8;
      const float* vbp = va + Dm;  // next key
      float4 a0 = *(const float4*)(va);
      float4 a1 = *(const float4*)(va + 4);
      float4 b0 = *(const float4*)(vbp);
      float4 b1 = *(const float4*)(vbp + 4);
      float av[8] = {a0.x, a0.y, a0.z, a0.w, a1.x, a1.y, a1.z, a1.w};
      float bv[8] = {b0.x, b0.y, b0.z, b0.w, b1.x, b1.y, b1.z, b1.w};
#pragma unroll
      for (int i = 0; i < 8; ++i) {
        const int d = vdg * 8 + i;
        uint32_t pk = (uint32_t)f2bf(av[i]) | ((uint32_t)f2bf(bv[i]) << 16);
        ((uint32_t*)&Vt[d][0])[vkp] = pk;
      }
    }
    // ---- stage mask words ----
    if (tid < 64) mw[tid] = mask[((size_t)(b * Lq + q0 + tid)) * (Lq / 32) + kt];
    __syncthreads();

    // ---- S = Q K^T (two 16-key halves) ----
    f32x4 acc0 = (f32x4){0.f, 0.f, 0.f, 0.f};
    f32x4 acc1 = acc0;
#pragma unroll
    for (int kk = 0; kk < 4; ++kk) {
      bf16x8 b0 = *(const bf16x8*)&Ks[l15][kk * 32 + quad * 8];
      bf16x8 b1 = *(const bf16x8*)&Ks[16 + l15][kk * 32 + quad * 8];
      acc0 = __builtin_amdgcn_mfma_f32_16x16x32_bf16(aq[kk], b0, acc0, 0, 0, 0);
      acc1 = __builtin_amdgcn_mfma_f32_16x16x32_bf16(aq[kk], b1, acc1, 0, 0, 0);
    }

    // ---- online softmax per q-row (rows = quad*4 + r) ----
#pragma unroll
    for (int r = 0; r < 4; ++r) {
      const int ql = w * 16 + quad * 4 + r;
      const uint32_t mword = mw[ql];
      float s0 = ((mword >> l15) & 1u) ? acc0[r] * scale : NEG_INF;
      float s1 = ((mword >> (16 + l15)) & 1u) ? acc1[r] * scale : NEG_INF;
      float rm = fmaxf(s0, s1);
      rm = fmaxf(rm, __shfl_xor(rm, 1));
      rm = fmaxf(rm, __shfl_xor(rm, 2));
      rm = fmaxf(rm, __shfl_xor(rm, 4));
      rm = fmaxf(rm, __shfl_xor(rm, 8));
      const float mn = fmaxf(m_[r], rm);
      const float alpha = (m_[r] == mn) ? 1.0f : exp2f((m_[r] - mn) * L2E);
      const float p0 = (s0 == NEG_INF) ? 0.0f : exp2f((s0 - mn) * L2E);
      const float p1 = (s1 == NEG_INF) ? 0.0f : exp2f((s1 - mn) * L2E);
      float rs = p0 + p1;
      rs += __shfl_xor(rs, 1);
      rs += __shfl_xor(rs, 2);
      rs += __shfl_xor(rs, 4);
      rs += __shfl_xor(rs, 8);
      l_[r] = l_[r] * alpha + rs;
      m_[r] = mn;
#pragma unroll
      for (int f = 0; f < 8; ++f) O[f][r] *= alpha;
      Ps[w][quad * 4 + r][l15] = f2bf(p0);
      Ps[w][quad * 4 + r][16 + l15] = f2bf(p1);
    }
    __syncthreads();

    // ---- O += P V ----
    bf16x8 ap = *(const bf16x8*)&Ps[w][l15][quad * 8];
#pragma unroll
    for (int f = 0; f < 8; ++f) {
      bf16x8 bv = *(const bf16x8*)&Vt[f * 16 + l15][quad * 8];
      O[f] = __builtin_amdgcn_mfma_f32_16x16x32_bf16(ap, bv, O[f], 0, 0, 0);
    }
    __syncthreads();
  }

  // ---- epilogue: ctx = O / l ----
#pragma unroll
  for (int r = 0; r < 4; ++r) {
    const int q = q0 + w * 16 + quad * 4 + r;
    const float rl = 1.0f / l_[r];
    float* orow = ctx + ((size_t)(b * Lq + q)) * Dm + h * DH;
#pragma unroll
    for (int f = 0; f < 8; ++f) orow[f * 16 + l15] = O[f][r] * rl;
  }
}

// ---------------------------------------------------------------------------
extern "C" void kernel_launch(void* const* d_in, const int* in_sizes, int n_in,
                              void* d_out, int out_size, void* d_ws, size_t ws_size,
                              hipStream_t stream) {
  const float* hs  = (const float*)d_in[0];
  const float* rel = (const float*)d_in[1];
  const float* Wqr = (const float*)d_in[2];
  const float* Wkr = (const float*)d_in[3];
  const float* Wq  = (const float*)d_in[4];
  const float* Wk  = (const float*)d_in[5];
  const float* Wv  = (const float*)d_in[6];
  const float* Wo  = (const float*)d_in[7];
  float* out = (float*)d_out;

  float* ws = (float*)d_ws;
  const int M = Bb * Lq;  // 4096
  size_t off = 0;
  float* qrel = ws + off; off += (size_t)M * DREL;
  float* krel = ws + off; off += (size_t)M * DREL;
  float* qb   = ws + off; off += (size_t)M * Dm;
  float* kb   = ws + off; off += (size_t)M * Dm;
  float* vb   = ws + off; off += (size_t)M * Dm;
  float* ctx  = ws + off; off += (size_t)M * Dm;
  uint32_t* maskb = (uint32_t*)(ws + off);  // M * 64 words

  const dim3 blk(256);

  gemm_nt<<<dim3(1, M / BM), blk, 0, stream>>>(rel, Wqr, qrel, M, DREL, Dm);
  gemm_nt<<<dim3(1, M / BM), blk, 0, stream>>>(rel, Wkr, krel, M, DREL, Dm);

  gemm_nt<<<dim3(Dm / BN, M / BM), blk, 0, stream>>>(hs, Wq, qb, M, Dm, Dm);
  gemm_nt<<<dim3(Dm / BN, M / BM), blk, 0, stream>>>(hs, Wk, kb, M, Dm, Dm);
  gemm_nt<<<dim3(Dm / BN, M / BM), blk, 0, stream>>>(hs, Wv, vb, M, Dm, Dm);

  relmask_kernel<<<M, blk, 0, stream>>>(qrel, krel, maskb);

  attn_flash<<<dim3(Lq / 64, Hh, Bb), blk, 0, stream>>>(qb, kb, vb, maskb, ctx);

  gemm_nt<<<dim3(Dm / BN, M / BM), blk, 0, stream>>>(ctx, Wo, out, M, Dm, Dm);
}

// Round 3
// 1465.082 us; speedup vs baseline: 6.2970x; 2.0057x over previous
//
#include <hip/hip_runtime.h>
#include <math.h>
#include <stdint.h>

// Problem constants (match reference)
#define Bb 2
#define Lq 2048
#define Dm 2048
#define Hh 16
#define DH 128
#define DREL 64
#define KTOP 512   // 0.25 * L

#define NEG_INF (-__builtin_huge_valf())

typedef __attribute__((ext_vector_type(8))) short bf16x8;   // 8 bf16 (4 VGPRs)
typedef __attribute__((ext_vector_type(4))) float f32x4;

static __device__ __forceinline__ unsigned short f2bf(float f) {
  unsigned int u = __float_as_uint(f);
  u += 0x7fffu + ((u >> 16) & 1u);   // RNE
  return (unsigned short)(u >> 16);
}

// async global->LDS, 16B per lane; LDS dest = wave-uniform base + lane*16
static __device__ __forceinline__ void gload16(const void* g, void* lds) {
  __builtin_amdgcn_global_load_lds(
      (const __attribute__((address_space(1))) uint32_t*)(uintptr_t)g,
      (__attribute__((address_space(3))) uint32_t*)(uint32_t)(uintptr_t)lds,
      16, 0, 0);
}

// ---------------------------------------------------------------------------
// fp32 -> bf16 elementwise (n multiple of 8)
// ---------------------------------------------------------------------------
__global__ __launch_bounds__(256) void conv_bf16(const float* __restrict__ in,
                                                 unsigned short* __restrict__ out,
                                                 int n8) {
  const int i = blockIdx.x * 256 + threadIdx.x;
  if (i >= n8) return;
  const float4 f0 = ((const float4*)in)[2 * i];
  const float4 f1 = ((const float4*)in)[2 * i + 1];
  bf16x8 o;
  o[0] = (short)f2bf(f0.x); o[1] = (short)f2bf(f0.y);
  o[2] = (short)f2bf(f0.z); o[3] = (short)f2bf(f0.w);
  o[4] = (short)f2bf(f1.x); o[5] = (short)f2bf(f1.y);
  o[6] = (short)f2bf(f1.z); o[7] = (short)f2bf(f1.w);
  *(bf16x8*)(out + 8 * (size_t)i) = o;
}

// ---------------------------------------------------------------------------
// bf16 MFMA GEMM (m97 structure): C[M,N] = A[M,K] @ W[N,K]^T, fp32 accum.
// 128x128 tile, BK=32, 256 thr = 4 waves (2x2), each wave 64x64 via 4x4 MFMA.
// A,W bf16 row-major; C fp32 or bf16 (template).
// ---------------------------------------------------------------------------
template <bool BF16OUT>
__global__ __launch_bounds__(256) void gemm_bf(const unsigned short* __restrict__ A,
                                               const unsigned short* __restrict__ W,
                                               void* __restrict__ Cv,
                                               int M, int N, int Kd) {
  __shared__ unsigned short As[128][32];
  __shared__ unsigned short Bs[128][32];
  const int tid = threadIdx.x;
  const int w = tid >> 6;
  const int lane = tid & 63;
  const int l15 = lane & 15;
  const int quad = lane >> 4;
  const int wm = w >> 1, wn = w & 1;
  const int m0 = blockIdx.y * 128, n0 = blockIdx.x * 128;

  const int srow = lane >> 2;        // 0..15
  const int scol = (lane & 3) * 8;   // element col (8 bf16 = 16B)

  const unsigned short* aR0 = A + (size_t)(m0 + w * 32 + srow) * Kd + scol;
  const unsigned short* aR1 = aR0 + (size_t)16 * Kd;
  const unsigned short* bR0 = W + (size_t)(n0 + w * 32 + srow) * Kd + scol;
  const unsigned short* bR1 = bR0 + (size_t)16 * Kd;

  f32x4 acc[4][4];
#pragma unroll
  for (int i = 0; i < 4; ++i)
#pragma unroll
    for (int j = 0; j < 4; ++j) acc[i][j] = (f32x4){0.f, 0.f, 0.f, 0.f};

  for (int k0 = 0; k0 < Kd; k0 += 32) {
    gload16(aR0 + k0, &As[w * 32][0]);
    gload16(aR1 + k0, &As[w * 32 + 16][0]);
    gload16(bR0 + k0, &Bs[w * 32][0]);
    gload16(bR1 + k0, &Bs[w * 32 + 16][0]);
    __syncthreads();

    bf16x8 af[4], bfr[4];
#pragma unroll
    for (int im = 0; im < 4; ++im)
      af[im] = *(const bf16x8*)&As[wm * 64 + im * 16 + l15][quad * 8];
#pragma unroll
    for (int in = 0; in < 4; ++in)
      bfr[in] = *(const bf16x8*)&Bs[wn * 64 + in * 16 + l15][quad * 8];
#pragma unroll
    for (int im = 0; im < 4; ++im)
#pragma unroll
      for (int in = 0; in < 4; ++in)
        acc[im][in] = __builtin_amdgcn_mfma_f32_16x16x32_bf16(af[im], bfr[in], acc[im][in], 0, 0, 0);
    __syncthreads();
  }

#pragma unroll
  for (int im = 0; im < 4; ++im) {
#pragma unroll
    for (int in = 0; in < 4; ++in) {
      const int col = n0 + wn * 64 + in * 16 + l15;
#pragma unroll
      for (int r = 0; r < 4; ++r) {
        const int row = m0 + wm * 64 + im * 16 + quad * 4 + r;
        if (BF16OUT)
          ((unsigned short*)Cv)[(size_t)row * N + col] = f2bf(acc[im][in][r]);
        else
          ((float*)Cv)[(size_t)row * N + col] = acc[im][in][r];
      }
    }
  }
}

// ---------------------------------------------------------------------------
// fp32 tiled GEMM (kept for rel projections; selection must stay fp32-exact)
// ---------------------------------------------------------------------------
#define BM 128
#define BN 128
#define BK 16
#define TM 8
#define TN 8

__global__ __launch_bounds__(256) void gemm_nt(const float* __restrict__ A,
                                               const float* __restrict__ W,
                                               float* __restrict__ C,
                                               int M, int N, int Kd) {
  __shared__ float As[BK][BM];
  __shared__ float Bs[BK][BN];
  const int tid = threadIdx.x;
  const int m0 = blockIdx.y * BM;
  const int n0 = blockIdx.x * BN;
  const int tx = tid & 15;
  const int ty = tid >> 4;
  const int lr = tid >> 1;
  const int lk = (tid & 1) * 8;

  float acc[TM][TN];
#pragma unroll
  for (int i = 0; i < TM; ++i)
#pragma unroll
    for (int j = 0; j < TN; ++j) acc[i][j] = 0.0f;

  for (int k0 = 0; k0 < Kd; k0 += BK) {
    {
      const int gm = m0 + lr;
      float4 a0 = make_float4(0, 0, 0, 0), a1 = a0;
      if (gm < M) {
        const float* ap = A + (size_t)gm * Kd + k0 + lk;
        a0 = *(const float4*)(ap);
        a1 = *(const float4*)(ap + 4);
      }
      As[lk + 0][lr] = a0.x; As[lk + 1][lr] = a0.y;
      As[lk + 2][lr] = a0.z; As[lk + 3][lr] = a0.w;
      As[lk + 4][lr] = a1.x; As[lk + 5][lr] = a1.y;
      As[lk + 6][lr] = a1.z; As[lk + 7][lr] = a1.w;
    }
    {
      const int gn = n0 + lr;
      float4 b0 = make_float4(0, 0, 0, 0), b1 = b0;
      if (gn < N) {
        const float* bp = W + (size_t)gn * Kd + k0 + lk;
        b0 = *(const float4*)(bp);
        b1 = *(const float4*)(bp + 4);
      }
      Bs[lk + 0][lr] = b0.x; Bs[lk + 1][lr] = b0.y;
      Bs[lk + 2][lr] = b0.z; Bs[lk + 3][lr] = b0.w;
      Bs[lk + 4][lr] = b1.x; Bs[lk + 5][lr] = b1.y;
      Bs[lk + 6][lr] = b1.z; Bs[lk + 7][lr] = b1.w;
    }
    __syncthreads();

#pragma unroll
    for (int kk = 0; kk < BK; ++kk) {
      float af[TM], bf[TN];
#pragma unroll
      for (int i = 0; i < TM; ++i) af[i] = As[kk][ty * TM + i];
#pragma unroll
      for (int j = 0; j < TN; ++j) bf[j] = Bs[kk][tx * TN + j];
#pragma unroll
      for (int i = 0; i < TM; ++i)
#pragma unroll
        for (int j = 0; j < TN; ++j) acc[i][j] += af[i] * bf[j];
    }
    __syncthreads();
  }

  const int gn = n0 + tx * TN;
  if (gn < N) {
#pragma unroll
    for (int i = 0; i < TM; ++i) {
      const int gm = m0 + ty * TM + i;
      if (gm < M) {
        float4* cp = (float4*)(C + (size_t)gm * N + gn);
        cp[0] = make_float4(acc[i][0], acc[i][1], acc[i][2], acc[i][3]);
        cp[1] = make_float4(acc[i][4], acc[i][5], acc[i][6], acc[i][7]);
      }
    }
  }
}

// ---------------------------------------------------------------------------
// Per-(b,q) rel-score + exact top-K (radix select, fp32 total order) -> bitmask
// ---------------------------------------------------------------------------
__global__ __launch_bounds__(256) void relmask_kernel(const float* __restrict__ qrel,
                                                      const float* __restrict__ krel,
                                                      uint32_t* __restrict__ mask) {
  const int bid = blockIdx.x;
  const int qi = bid % Lq;
  const int b = bid / Lq;
  const int tid = threadIdx.x;

  __shared__ float qv[DREL];
  __shared__ uint32_t keys[Lq];
  __shared__ uint32_t prefix_s;
  __shared__ int r_s;
  __shared__ int cnt_s;

  if (tid < DREL) qv[tid] = qrel[((size_t)(b * Lq + qi)) * DREL + tid];
  __syncthreads();

  const int n = qi + 1;

  for (int j = tid; j < Lq; j += 256) {
    uint32_t key = 0u;
    if (j < n) {
      const float4* kp = (const float4*)(krel + ((size_t)(b * Lq + j)) * DREL);
      float acc = 0.0f;
#pragma unroll
      for (int t = 0; t < DREL / 4; ++t) {
        float4 k4 = kp[t];
        acc += qv[4 * t + 0] * k4.x + qv[4 * t + 1] * k4.y +
               qv[4 * t + 2] * k4.z + qv[4 * t + 3] * k4.w;
      }
      const float s = acc * 0.125f;  // DREL^-0.5
      uint32_t u = __float_as_uint(s);
      key = (u & 0x80000000u) ? ~u : (u | 0x80000000u);
    }
    keys[j] = key;
  }

  uint32_t kth = 0u;
  if (n > KTOP) {
    if (tid == 0) { prefix_s = 0u; r_s = KTOP; }
    __syncthreads();
    for (int bit = 31; bit >= 0; --bit) {
      const uint32_t cand_hi = (prefix_s >> bit) | 1u;
      int local = 0;
      for (int j = tid; j < n; j += 256)
        if ((keys[j] >> bit) == cand_hi) local++;
      if (tid == 0) cnt_s = 0;
      __syncthreads();
      if (local) atomicAdd(&cnt_s, local);
      __syncthreads();
      if (tid == 0) {
        if (cnt_s >= r_s) prefix_s |= (1u << bit);
        else r_s -= cnt_s;
      }
      __syncthreads();
    }
    kth = prefix_s;
  }
  __syncthreads();

  for (int w = tid; w < Lq / 32; w += 256) {
    uint32_t word = 0u;
#pragma unroll
    for (int i = 0; i < 32; ++i) {
      const int j = w * 32 + i;
      const bool ok = (j < n) && ((n <= KTOP) || (keys[j] >= kth) || (j == qi));
      if (ok) word |= (1u << i);
    }
    mask[((size_t)(b * Lq + qi)) * (Lq / 32) + w] = word;
  }
}

// ---------------------------------------------------------------------------
// Dense flash attention with additive bitmask, bf16 MFMA (16x16x32).
// Q/K/V/ctx are bf16. 256 thr = 4 waves, each wave 16 q-rows -> TQ=64, TK=32.
// ---------------------------------------------------------------------------
__global__ __launch_bounds__(256) void attn_flash(const unsigned short* __restrict__ qb,
                                                  const unsigned short* __restrict__ kb,
                                                  const unsigned short* __restrict__ vb,
                                                  const uint32_t* __restrict__ mask,
                                                  unsigned short* __restrict__ ctx) {
  __shared__ unsigned short Ks[32][136];   // [key][dim]
  __shared__ unsigned short Vt[128][40];   // [dim][key]
  __shared__ unsigned short Ps[4][16][40]; // per-wave P tile [m][key]
  __shared__ uint32_t mw[64];

  const int qt = (int)gridDim.x - 1 - (int)blockIdx.x;  // heavy blocks first
  const int h = blockIdx.y;
  const int b = blockIdx.z;
  const int tid = threadIdx.x;
  const int w = tid >> 6;
  const int lane = tid & 63;
  const int l15 = lane & 15;
  const int quad = lane >> 4;

  const int q0 = qt * 64;
  const float scale = 0.08838834764831845f;  // DH^-0.5
  const float L2E = 1.4426950408889634f;

  const int myq = q0 + w * 16 + l15;
  const unsigned short* qrow = qb + ((size_t)(b * Lq + myq)) * Dm + h * DH;
  bf16x8 aq[4];
#pragma unroll
  for (int kk = 0; kk < 4; ++kk) aq[kk] = *(const bf16x8*)(qrow + kk * 32 + quad * 8);

  f32x4 O[8];
#pragma unroll
  for (int f = 0; f < 8; ++f) O[f] = (f32x4){0.f, 0.f, 0.f, 0.f};
  float m_[4] = {NEG_INF, NEG_INF, NEG_INF, NEG_INF};
  float l_[4] = {0.f, 0.f, 0.f, 0.f};

  const int nt = (q0 + 64) / 32;

  const int skey = tid >> 3;          // 0..31
  const int scg = tid & 7;            // 0..7 -> dims scg*16..+16
  const int vkp = tid & 15;           // key pair
  const int vdg = tid >> 4;           // 0..15 -> dims vdg*8..+8

  for (int kt = 0; kt < nt; ++kt) {
    const int kbase = kt * 32;
    {
      const unsigned short* kr = kb + ((size_t)(b * Lq + kbase + skey)) * Dm + h * DH + scg * 16;
      bf16x8 lo = *(const bf16x8*)(kr);
      bf16x8 hi = *(const bf16x8*)(kr + 8);
      *(bf16x8*)&Ks[skey][scg * 16] = lo;
      *(bf16x8*)&Ks[skey][scg * 16 + 8] = hi;
    }
    {
      const unsigned short* va = vb + ((size_t)(b * Lq + kbase + 2 * vkp)) * Dm + h * DH + vdg * 8;
      bf16x8 a8 = *(const bf16x8*)(va);
      bf16x8 b8 = *(const bf16x8*)(va + Dm);
#pragma unroll
      for (int i = 0; i < 8; ++i) {
        const int d = vdg * 8 + i;
        uint32_t pk = (uint32_t)(unsigned short)a8[i] | ((uint32_t)(unsigned short)b8[i] << 16);
        ((uint32_t*)&Vt[d][0])[vkp] = pk;
      }
    }
    if (tid < 64) mw[tid] = mask[((size_t)(b * Lq + q0 + tid)) * (Lq / 32) + kt];
    __syncthreads();

    f32x4 acc0 = (f32x4){0.f, 0.f, 0.f, 0.f};
    f32x4 acc1 = acc0;
#pragma unroll
    for (int kk = 0; kk < 4; ++kk) {
      bf16x8 b0 = *(const bf16x8*)&Ks[l15][kk * 32 + quad * 8];
      bf16x8 b1 = *(const bf16x8*)&Ks[16 + l15][kk * 32 + quad * 8];
      acc0 = __builtin_amdgcn_mfma_f32_16x16x32_bf16(aq[kk], b0, acc0, 0, 0, 0);
      acc1 = __builtin_amdgcn_mfma_f32_16x16x32_bf16(aq[kk], b1, acc1, 0, 0, 0);
    }

#pragma unroll
    for (int r = 0; r < 4; ++r) {
      const int ql = w * 16 + quad * 4 + r;
      const uint32_t mword = mw[ql];
      float s0 = ((mword >> l15) & 1u) ? acc0[r] * scale : NEG_INF;
      float s1 = ((mword >> (16 + l15)) & 1u) ? acc1[r] * scale : NEG_INF;
      float rm = fmaxf(s0, s1);
      rm = fmaxf(rm, __shfl_xor(rm, 1));
      rm = fmaxf(rm, __shfl_xor(rm, 2));
      rm = fmaxf(rm, __shfl_xor(rm, 4));
      rm = fmaxf(rm, __shfl_xor(rm, 8));
      const float mn = fmaxf(m_[r], rm);
      const float alpha = (m_[r] == mn) ? 1.0f : exp2f((m_[r] - mn) * L2E);
      const float p0 = (s0 == NEG_INF) ? 0.0f : exp2f((s0 - mn) * L2E);
      const float p1 = (s1 == NEG_INF) ? 0.0f : exp2f((s1 - mn) * L2E);
      float rs = p0 + p1;
      rs += __shfl_xor(rs, 1);
      rs += __shfl_xor(rs, 2);
      rs += __shfl_xor(rs, 4);
      rs += __shfl_xor(rs, 8);
      l_[r] = l_[r] * alpha + rs;
      m_[r] = mn;
#pragma unroll
      for (int f = 0; f < 8; ++f) O[f][r] *= alpha;
      Ps[w][quad * 4 + r][l15] = f2bf(p0);
      Ps[w][quad * 4 + r][16 + l15] = f2bf(p1);
    }
    __syncthreads();

    bf16x8 ap = *(const bf16x8*)&Ps[w][l15][quad * 8];
#pragma unroll
    for (int f = 0; f < 8; ++f) {
      bf16x8 bv = *(const bf16x8*)&Vt[f * 16 + l15][quad * 8];
      O[f] = __builtin_amdgcn_mfma_f32_16x16x32_bf16(ap, bv, O[f], 0, 0, 0);
    }
    __syncthreads();
  }

#pragma unroll
  for (int r = 0; r < 4; ++r) {
    const int q = q0 + w * 16 + quad * 4 + r;
    const float rl = 1.0f / l_[r];
    unsigned short* orow = ctx + ((size_t)(b * Lq + q)) * Dm + h * DH;
#pragma unroll
    for (int f = 0; f < 8; ++f) orow[f * 16 + l15] = f2bf(O[f][r] * rl);
  }
}

// ---------------------------------------------------------------------------
extern "C" void kernel_launch(void* const* d_in, const int* in_sizes, int n_in,
                              void* d_out, int out_size, void* d_ws, size_t ws_size,
                              hipStream_t stream) {
  const float* hs  = (const float*)d_in[0];
  const float* rel = (const float*)d_in[1];
  const float* Wqr = (const float*)d_in[2];
  const float* Wkr = (const float*)d_in[3];
  const float* Wq  = (const float*)d_in[4];
  const float* Wk  = (const float*)d_in[5];
  const float* Wv  = (const float*)d_in[6];
  const float* Wo  = (const float*)d_in[7];
  float* out = (float*)d_out;

  const int M = Bb * Lq;   // 4096
  const int ND = Dm * Dm;  // 2048*2048
  char* ws = (char*)d_ws;
  size_t off = 0;
  float* qrel = (float*)(ws + off); off += (size_t)M * DREL * 4;
  float* krel = (float*)(ws + off); off += (size_t)M * DREL * 4;
  uint32_t* maskb = (uint32_t*)(ws + off); off += (size_t)M * (Lq / 32) * 4;
  unsigned short* hsb  = (unsigned short*)(ws + off); off += (size_t)M * Dm * 2;
  unsigned short* qb16 = (unsigned short*)(ws + off); off += (size_t)M * Dm * 2;
  unsigned short* kb16 = (unsigned short*)(ws + off); off += (size_t)M * Dm * 2;
  unsigned short* vb16 = (unsigned short*)(ws + off); off += (size_t)M * Dm * 2;
  unsigned short* ctxb = (unsigned short*)(ws + off); off += (size_t)M * Dm * 2;
  unsigned short* Wb   = (unsigned short*)(ws + off); off += (size_t)ND * 2;

  const dim3 blk(256);
  const int hsN8 = M * Dm / 8;   // 1M
  const int wN8  = ND / 8;       // 512K

  // rel projections (fp32-exact; feeds top-K selection)
  gemm_nt<<<dim3(1, M / BM), blk, 0, stream>>>(rel, Wqr, qrel, M, DREL, Dm);
  gemm_nt<<<dim3(1, M / BM), blk, 0, stream>>>(rel, Wkr, krel, M, DREL, Dm);
  relmask_kernel<<<M, blk, 0, stream>>>(qrel, krel, maskb);

  // bf16 conversions + MFMA GEMMs for Q/K/V (bf16 out)
  conv_bf16<<<(hsN8 + 255) / 256, blk, 0, stream>>>(hs, hsb, hsN8);
  const dim3 ggrid(Dm / 128, M / 128);
  conv_bf16<<<(wN8 + 255) / 256, blk, 0, stream>>>(Wq, Wb, wN8);
  gemm_bf<true><<<ggrid, blk, 0, stream>>>(hsb, Wb, qb16, M, Dm, Dm);
  conv_bf16<<<(wN8 + 255) / 256, blk, 0, stream>>>(Wk, Wb, wN8);
  gemm_bf<true><<<ggrid, blk, 0, stream>>>(hsb, Wb, kb16, M, Dm, Dm);
  conv_bf16<<<(wN8 + 255) / 256, blk, 0, stream>>>(Wv, Wb, wN8);
  gemm_bf<true><<<ggrid, blk, 0, stream>>>(hsb, Wb, vb16, M, Dm, Dm);

  // flash attention (bf16 in/out)
  attn_flash<<<dim3(Lq / 64, Hh, Bb), blk, 0, stream>>>(qb16, kb16, vb16, maskb, ctxb);

  // O projection -> fp32 out
  conv_bf16<<<(wN8 + 255) / 256, blk, 0, stream>>>(Wo, Wb, wN8);
  gemm_bf<false><<<ggrid, blk, 0, stream>>>(ctxb, Wb, out, M, Dm, Dm);
}

// Round 4
// 728.446 us; speedup vs baseline: 12.6647x; 2.0112x over previous
//
#include <hip/hip_runtime.h>
#include <math.h>
#include <stdint.h>

// Problem constants (match reference)
#define Bb 2
#define Lq 2048
#define Dm 2048
#define Hh 16
#define DH 128
#define DREL 64
#define KTOP 512   // 0.25 * L

#define NEG_INF (-__builtin_huge_valf())

typedef __attribute__((ext_vector_type(8))) short bf16x8;   // 8 bf16 (4 VGPRs)
typedef __attribute__((ext_vector_type(4))) float f32x4;

static __device__ __forceinline__ unsigned short f2bf(float f) {
  unsigned int u = __float_as_uint(f);
  u += 0x7fffu + ((u >> 16) & 1u);   // RNE
  return (unsigned short)(u >> 16);
}

// async global->LDS, 16B per lane; LDS dest = wave-uniform base + lane*16
static __device__ __forceinline__ void gload16(const void* g, void* lds) {
  __builtin_amdgcn_global_load_lds(
      (const __attribute__((address_space(1))) uint32_t*)(uintptr_t)g,
      (__attribute__((address_space(3))) uint32_t*)(uint32_t)(uintptr_t)lds,
      16, 0, 0);
}

// ---------------------------------------------------------------------------
// fp32 -> bf16 elementwise (n8 = n/8)
// ---------------------------------------------------------------------------
__global__ __launch_bounds__(256) void conv_bf16(const float* __restrict__ in,
                                                 unsigned short* __restrict__ out,
                                                 int n8) {
  const int i = blockIdx.x * 256 + threadIdx.x;
  if (i >= n8) return;
  const float4 f0 = ((const float4*)in)[2 * i];
  const float4 f1 = ((const float4*)in)[2 * i + 1];
  bf16x8 o;
  o[0] = (short)f2bf(f0.x); o[1] = (short)f2bf(f0.y);
  o[2] = (short)f2bf(f0.z); o[3] = (short)f2bf(f0.w);
  o[4] = (short)f2bf(f1.x); o[5] = (short)f2bf(f1.y);
  o[6] = (short)f2bf(f1.z); o[7] = (short)f2bf(f1.w);
  *(bf16x8*)(out + 8 * (size_t)i) = o;
}

// ---------------------------------------------------------------------------
// bf16 MFMA GEMM (m97 structure): C[M,N] = A[M,K] @ W[N,K]^T, fp32 accum.
// ---------------------------------------------------------------------------
template <bool BF16OUT>
__global__ __launch_bounds__(256) void gemm_bf(const unsigned short* __restrict__ A,
                                               const unsigned short* __restrict__ W,
                                               void* __restrict__ Cv,
                                               int M, int N, int Kd) {
  __shared__ unsigned short As[128][32];
  __shared__ unsigned short Bs[128][32];
  const int tid = threadIdx.x;
  const int w = tid >> 6;
  const int lane = tid & 63;
  const int l15 = lane & 15;
  const int quad = lane >> 4;
  const int wm = w >> 1, wn = w & 1;
  const int m0 = blockIdx.y * 128, n0 = blockIdx.x * 128;

  const int srow = lane >> 2;        // 0..15
  const int scol = (lane & 3) * 8;   // element col (8 bf16 = 16B)

  const unsigned short* aR0 = A + (size_t)(m0 + w * 32 + srow) * Kd + scol;
  const unsigned short* aR1 = aR0 + (size_t)16 * Kd;
  const unsigned short* bR0 = W + (size_t)(n0 + w * 32 + srow) * Kd + scol;
  const unsigned short* bR1 = bR0 + (size_t)16 * Kd;

  f32x4 acc[4][4];
#pragma unroll
  for (int i = 0; i < 4; ++i)
#pragma unroll
    for (int j = 0; j < 4; ++j) acc[i][j] = (f32x4){0.f, 0.f, 0.f, 0.f};

  for (int k0 = 0; k0 < Kd; k0 += 32) {
    gload16(aR0 + k0, &As[w * 32][0]);
    gload16(aR1 + k0, &As[w * 32 + 16][0]);
    gload16(bR0 + k0, &Bs[w * 32][0]);
    gload16(bR1 + k0, &Bs[w * 32 + 16][0]);
    __syncthreads();

    bf16x8 af[4], bfr[4];
#pragma unroll
    for (int im = 0; im < 4; ++im)
      af[im] = *(const bf16x8*)&As[wm * 64 + im * 16 + l15][quad * 8];
#pragma unroll
    for (int in = 0; in < 4; ++in)
      bfr[in] = *(const bf16x8*)&Bs[wn * 64 + in * 16 + l15][quad * 8];
#pragma unroll
    for (int im = 0; im < 4; ++im)
#pragma unroll
      for (int in = 0; in < 4; ++in)
        acc[im][in] = __builtin_amdgcn_mfma_f32_16x16x32_bf16(af[im], bfr[in], acc[im][in], 0, 0, 0);
    __syncthreads();
  }

#pragma unroll
  for (int im = 0; im < 4; ++im) {
#pragma unroll
    for (int in = 0; in < 4; ++in) {
      const int col = n0 + wn * 64 + in * 16 + l15;
#pragma unroll
      for (int r = 0; r < 4; ++r) {
        const int row = m0 + wm * 64 + im * 16 + quad * 4 + r;
        if (BF16OUT)
          ((unsigned short*)Cv)[(size_t)row * N + col] = f2bf(acc[im][in][r]);
        else
          ((float*)Cv)[(size_t)row * N + col] = acc[im][in][r];
      }
    }
  }
}

// ---------------------------------------------------------------------------
// Split-K fp32 rel projection: part[ks][128 rows][64 cols] over k-slice of 256.
// grid (RKS, M/128), 256 threads, micro-tile 8x4.
// ---------------------------------------------------------------------------
#define RKS 8
__global__ __launch_bounds__(256) void relproj(const float* __restrict__ A,
                                               const float* __restrict__ W,
                                               float* __restrict__ part, int M) {
  __shared__ float As[16][128];
  __shared__ float Bs[16][64];
  const int ks = blockIdx.x;
  const int m0 = blockIdx.y * 128;
  const int tid = threadIdx.x;
  const int tx = tid & 15;   // col group (4 cols)
  const int ty = tid >> 4;   // row group (8 rows)
  const int lr = tid >> 1, lk = (tid & 1) * 8;
  const int wr = tid >> 2, wk = (tid & 3) * 4;

  float acc[8][4];
#pragma unroll
  for (int i = 0; i < 8; ++i)
#pragma unroll
    for (int j = 0; j < 4; ++j) acc[i][j] = 0.f;

  const int k00 = ks * (Dm / RKS);
  for (int k0 = k00; k0 < k00 + Dm / RKS; k0 += 16) {
    {
      const float* ap = A + (size_t)(m0 + lr) * Dm + k0 + lk;
      float4 a0 = *(const float4*)(ap);
      float4 a1 = *(const float4*)(ap + 4);
      As[lk + 0][lr] = a0.x; As[lk + 1][lr] = a0.y;
      As[lk + 2][lr] = a0.z; As[lk + 3][lr] = a0.w;
      As[lk + 4][lr] = a1.x; As[lk + 5][lr] = a1.y;
      As[lk + 6][lr] = a1.z; As[lk + 7][lr] = a1.w;
    }
    {
      const float* bp = W + (size_t)wr * Dm + k0 + wk;
      float4 b0 = *(const float4*)(bp);
      Bs[wk + 0][wr] = b0.x; Bs[wk + 1][wr] = b0.y;
      Bs[wk + 2][wr] = b0.z; Bs[wk + 3][wr] = b0.w;
    }
    __syncthreads();
#pragma unroll
    for (int kk = 0; kk < 16; ++kk) {
      float af[8], bf[4];
#pragma unroll
      for (int i = 0; i < 8; ++i) af[i] = As[kk][ty * 8 + i];
#pragma unroll
      for (int j = 0; j < 4; ++j) bf[j] = Bs[kk][tx * 4 + j];
#pragma unroll
      for (int i = 0; i < 8; ++i)
#pragma unroll
        for (int j = 0; j < 4; ++j) acc[i][j] += af[i] * bf[j];
    }
    __syncthreads();
  }

#pragma unroll
  for (int i = 0; i < 8; ++i) {
    float* pp = part + ((size_t)ks * M + m0 + ty * 8 + i) * DREL + tx * 4;
    *(float4*)pp = make_float4(acc[i][0], acc[i][1], acc[i][2], acc[i][3]);
  }
}

__global__ __launch_bounds__(256) void relreduce(const float* __restrict__ pq,
                                                 const float* __restrict__ pk,
                                                 float* __restrict__ qrel,
                                                 float* __restrict__ krel, int n4) {
  const int i = blockIdx.x * 256 + threadIdx.x;
  if (i >= n4) return;
  float4 sq = make_float4(0, 0, 0, 0), sk = sq;
  for (int s = 0; s < RKS; ++s) {
    float4 a = ((const float4*)pq)[(size_t)s * n4 + i];
    float4 b = ((const float4*)pk)[(size_t)s * n4 + i];
    sq.x += a.x; sq.y += a.y; sq.z += a.z; sq.w += a.w;
    sk.x += b.x; sk.y += b.y; sk.z += b.z; sk.w += b.w;
  }
  ((float4*)qrel)[i] = sq;
  ((float4*)krel)[i] = sk;
}

// ---------------------------------------------------------------------------
// Per-(b,q) rel-score + exact top-K (radix select, fp32 total order) -> bitmask
// ---------------------------------------------------------------------------
__global__ __launch_bounds__(256) void relmask_kernel(const float* __restrict__ qrel,
                                                      const float* __restrict__ krel,
                                                      uint32_t* __restrict__ mask) {
  const int bid = blockIdx.x;
  const int qi = bid % Lq;
  const int b = bid / Lq;
  const int tid = threadIdx.x;

  __shared__ float qv[DREL];
  __shared__ uint32_t keys[Lq];
  __shared__ uint32_t prefix_s;
  __shared__ int r_s;
  __shared__ int cnt_s;

  if (tid < DREL) qv[tid] = qrel[((size_t)(b * Lq + qi)) * DREL + tid];
  __syncthreads();

  const int n = qi + 1;

  for (int j = tid; j < Lq; j += 256) {
    uint32_t key = 0u;
    if (j < n) {
      const float4* kp = (const float4*)(krel + ((size_t)(b * Lq + j)) * DREL);
      float acc = 0.0f;
#pragma unroll
      for (int t = 0; t < DREL / 4; ++t) {
        float4 k4 = kp[t];
        acc += qv[4 * t + 0] * k4.x + qv[4 * t + 1] * k4.y +
               qv[4 * t + 2] * k4.z + qv[4 * t + 3] * k4.w;
      }
      const float s = acc * 0.125f;  // DREL^-0.5
      uint32_t u = __float_as_uint(s);
      key = (u & 0x80000000u) ? ~u : (u | 0x80000000u);
    }
    keys[j] = key;
  }

  uint32_t kth = 0u;
  if (n > KTOP) {
    if (tid == 0) { prefix_s = 0u; r_s = KTOP; }
    __syncthreads();
    for (int bit = 31; bit >= 0; --bit) {
      const uint32_t cand_hi = (prefix_s >> bit) | 1u;
      int local = 0;
      for (int j = tid; j < n; j += 256)
        if ((keys[j] >> bit) == cand_hi) local++;
      if (tid == 0) cnt_s = 0;
      __syncthreads();
      if (local) atomicAdd(&cnt_s, local);
      __syncthreads();
      if (tid == 0) {
        if (cnt_s >= r_s) prefix_s |= (1u << bit);
        else r_s -= cnt_s;
      }
      __syncthreads();
    }
    kth = prefix_s;
  }
  __syncthreads();

  for (int w = tid; w < Lq / 32; w += 256) {
    uint32_t word = 0u;
#pragma unroll
    for (int i = 0; i < 32; ++i) {
      const int j = w * 32 + i;
      const bool ok = (j < n) && ((n <= KTOP) || (keys[j] >= kth) || (j == qi));
      if (ok) word |= (1u << i);
    }
    mask[((size_t)(b * Lq + qi)) * (Lq / 32) + w] = word;
  }
}

// ---------------------------------------------------------------------------
// Flash attention v2: S^T formulation, no-max softmax (shift-invariant),
// P stays in registers. 512 thr = 8 waves, TQ=128, TK=32.
//   S^T = K·Q^T : A-frag = K (m=key), B-frag = Q (n=q-row)
//     -> C layout: lane l15 = q-row, quad*4+r = key (acc0: keys 0-15, acc1: 16-31)
//   O^T = V^T·P^T : A-frag = V^T (m=dim), B-frag = P^T built in-register
//     B slot (quad,j): phys key = j<4 ? 4*quad+j : 16+4*quad+(j-4)
//   V staged in LDS with matching column permutation + pair-interleaved rows
//   (write conflicts 2-way = free).
// ---------------------------------------------------------------------------
#define ATQ 128
__global__ __launch_bounds__(512) void attn_flash2(const unsigned short* __restrict__ qb,
                                                   const unsigned short* __restrict__ kb,
                                                   const unsigned short* __restrict__ vb,
                                                   const uint32_t* __restrict__ mask,
                                                   unsigned short* __restrict__ ctx) {
  __shared__ unsigned short Ks[32][136];  // [key][dim]+pad
  __shared__ unsigned short Vt[64][72];   // row=d>>1, col=(d&1)*32 + slot
  __shared__ uint32_t mw[ATQ];

  const int qt = (int)gridDim.x - 1 - (int)blockIdx.x;  // heavy blocks first
  const int h = blockIdx.y;
  const int b = blockIdx.z;
  const int tid = threadIdx.x;
  const int w = tid >> 6;          // wave 0..7
  const int lane = tid & 63;
  const int l15 = lane & 15;
  const int quad = lane >> 4;

  const int q0 = qt * ATQ;
  const float C = 0.08838834764831845f * 1.4426950408889634f;  // DH^-0.5 * log2(e)

  // Q B-frag: lane holds Q[q=l15-row][dims quad*8.. (+kk*32)]
  const int myq = q0 + w * 16 + l15;
  const unsigned short* qrow = qb + ((size_t)(b * Lq + myq)) * Dm + h * DH;
  bf16x8 bq[4];
#pragma unroll
  for (int kk = 0; kk < 4; ++kk) bq[kk] = *(const bf16x8*)(qrow + kk * 32 + quad * 8);

  f32x4 O[8];  // O^T: O[f][r] = ctx[q=l15][f*16 + quad*4 + r]
#pragma unroll
  for (int f = 0; f < 8; ++f) O[f] = (f32x4){0.f, 0.f, 0.f, 0.f};
  float l_lane = 0.f;

  const int nt = (q0 + ATQ) / 32;

  // staging roles: waves 0-3 stage K, waves 4-7 stage V
  const int skey = (tid & 255) >> 3;   // 0..31
  const int scg = tid & 7;             // 0..7 -> dims scg*16..+16
  const int tv = tid - 256;
  const int vkp = tv & 15;             // key pair v
  const int vdg = tv >> 4;             // 0..15 -> dims vdg*8..+8
  // dword column for key pair v: g=(v>>1)&3, hlf=v>>3 -> g*4 + hlf*2 + (v&1)
  const int dwc = ((vkp >> 1) & 3) * 4 + (vkp >> 3) * 2 + (vkp & 1);

  for (int kt = 0; kt < nt; ++kt) {
    const int kbase = kt * 32;
    if (tid < 256) {
      const unsigned short* kr = kb + ((size_t)(b * Lq + kbase + skey)) * Dm + h * DH + scg * 16;
      bf16x8 lo = *(const bf16x8*)(kr);
      bf16x8 hi = *(const bf16x8*)(kr + 8);
      *(bf16x8*)&Ks[skey][scg * 16] = lo;
      *(bf16x8*)&Ks[skey][scg * 16 + 8] = hi;
    } else {
      const unsigned short* va = vb + ((size_t)(b * Lq + kbase + 2 * vkp)) * Dm + h * DH + vdg * 8;
      bf16x8 a8 = *(const bf16x8*)(va);
      bf16x8 b8 = *(const bf16x8*)(va + Dm);
#pragma unroll
      for (int i = 0; i < 8; ++i) {
        const int d = vdg * 8 + i;
        uint32_t pk = (uint32_t)(unsigned short)a8[i] | ((uint32_t)(unsigned short)b8[i] << 16);
        ((uint32_t*)&Vt[d >> 1][0])[(d & 1) * 16 + dwc] = pk;
      }
    }
    if (tid < ATQ) mw[tid] = mask[((size_t)(b * Lq + q0 + tid)) * (Lq / 32) + kt];
    __syncthreads();

    // S^T = K Q^T
    f32x4 acc0 = (f32x4){0.f, 0.f, 0.f, 0.f};
    f32x4 acc1 = acc0;
#pragma unroll
    for (int kk = 0; kk < 4; ++kk) {
      bf16x8 a0 = *(const bf16x8*)&Ks[l15][kk * 32 + quad * 8];
      bf16x8 a1 = *(const bf16x8*)&Ks[16 + l15][kk * 32 + quad * 8];
      acc0 = __builtin_amdgcn_mfma_f32_16x16x32_bf16(a0, bq[kk], acc0, 0, 0, 0);
      acc1 = __builtin_amdgcn_mfma_f32_16x16x32_bf16(a1, bq[kk], acc1, 0, 0, 0);
    }

    // softmax numerator (no max shift), build P^T B-frag in registers
    const uint32_t mword = mw[w * 16 + l15];
    bf16x8 bp;
    float ps = 0.f;
#pragma unroll
    for (int r = 0; r < 4; ++r) {
      const float p0 = ((mword >> (quad * 4 + r)) & 1u) ? __builtin_amdgcn_exp2f(acc0[r] * C) : 0.f;
      const float p1 = ((mword >> (16 + quad * 4 + r)) & 1u) ? __builtin_amdgcn_exp2f(acc1[r] * C) : 0.f;
      ps += p0 + p1;
      bp[r] = (short)f2bf(p0);
      bp[4 + r] = (short)f2bf(p1);
    }
    l_lane += ps;

    // O^T += V^T P^T
#pragma unroll
    for (int f = 0; f < 8; ++f) {
      const int d = f * 16 + l15;
      bf16x8 av = *(const bf16x8*)&Vt[d >> 1][(d & 1) * 32 + quad * 8];
      O[f] = __builtin_amdgcn_mfma_f32_16x16x32_bf16(av, bp, O[f], 0, 0, 0);
    }
    __syncthreads();
  }

  // reduce l across quads (lanes with same l15 hold same q-row)
  l_lane += __shfl_xor(l_lane, 16);
  l_lane += __shfl_xor(l_lane, 32);
  const float rl = 1.0f / l_lane;

  // epilogue: lane l15 = q-row; dims f*16 + quad*4 + r
  unsigned short* orow = ctx + ((size_t)(b * Lq + q0 + w * 16 + l15)) * Dm + h * DH;
#pragma unroll
  for (int f = 0; f < 8; ++f) {
    ushort4 o4;
    o4.x = f2bf(O[f][0] * rl);
    o4.y = f2bf(O[f][1] * rl);
    o4.z = f2bf(O[f][2] * rl);
    o4.w = f2bf(O[f][3] * rl);
    *(ushort4*)(orow + f * 16 + quad * 4) = o4;
  }
}

// ---------------------------------------------------------------------------
extern "C" void kernel_launch(void* const* d_in, const int* in_sizes, int n_in,
                              void* d_out, int out_size, void* d_ws, size_t ws_size,
                              hipStream_t stream) {
  const float* hs  = (const float*)d_in[0];
  const float* rel = (const float*)d_in[1];
  const float* Wqr = (const float*)d_in[2];
  const float* Wkr = (const float*)d_in[3];
  const float* Wq  = (const float*)d_in[4];
  const float* Wk  = (const float*)d_in[5];
  const float* Wv  = (const float*)d_in[6];
  const float* Wo  = (const float*)d_in[7];
  float* out = (float*)d_out;

  const int M = Bb * Lq;   // 4096
  const int ND = Dm * Dm;
  char* ws = (char*)d_ws;
  size_t off = 0;
  float* qrel = (float*)(ws + off); off += (size_t)M * DREL * 4;
  float* krel = (float*)(ws + off); off += (size_t)M * DREL * 4;
  float* partq = (float*)(ws + off); off += (size_t)RKS * M * DREL * 4;
  float* partk = (float*)(ws + off); off += (size_t)RKS * M * DREL * 4;
  uint32_t* maskb = (uint32_t*)(ws + off); off += (size_t)M * (Lq / 32) * 4;
  unsigned short* hsb  = (unsigned short*)(ws + off); off += (size_t)M * Dm * 2;
  unsigned short* qb16 = (unsigned short*)(ws + off); off += (size_t)M * Dm * 2;
  unsigned short* kb16 = (unsigned short*)(ws + off); off += (size_t)M * Dm * 2;
  unsigned short* vb16 = (unsigned short*)(ws + off); off += (size_t)M * Dm * 2;
  unsigned short* ctxb = (unsigned short*)(ws + off); off += (size_t)M * Dm * 2;
  unsigned short* Wqb  = (unsigned short*)(ws + off); off += (size_t)ND * 2;
  unsigned short* Wkb  = (unsigned short*)(ws + off); off += (size_t)ND * 2;
  unsigned short* Wvb  = (unsigned short*)(ws + off); off += (size_t)ND * 2;
  unsigned short* Wob  = (unsigned short*)(ws + off); off += (size_t)ND * 2;

  const dim3 blk(256);
  const int hsN8 = M * Dm / 8;
  const int wN8  = ND / 8;

  // rel projections (fp32-exact, split-K deterministic) + top-K mask
  relproj<<<dim3(RKS, M / 128), blk, 0, stream>>>(rel, Wqr, partq, M);
  relproj<<<dim3(RKS, M / 128), blk, 0, stream>>>(rel, Wkr, partk, M);
  relreduce<<<(M * DREL / 4 + 255) / 256, blk, 0, stream>>>(partq, partk, qrel, krel, M * DREL / 4);
  relmask_kernel<<<M, blk, 0, stream>>>(qrel, krel, maskb);

  // bf16 conversions
  conv_bf16<<<(hsN8 + 255) / 256, blk, 0, stream>>>(hs, hsb, hsN8);
  conv_bf16<<<(wN8 + 255) / 256, blk, 0, stream>>>(Wq, Wqb, wN8);
  conv_bf16<<<(wN8 + 255) / 256, blk, 0, stream>>>(Wk, Wkb, wN8);
  conv_bf16<<<(wN8 + 255) / 256, blk, 0, stream>>>(Wv, Wvb, wN8);
  conv_bf16<<<(wN8 + 255) / 256, blk, 0, stream>>>(Wo, Wob, wN8);

  // QKV projections (bf16 MFMA)
  const dim3 ggrid(Dm / 128, M / 128);
  gemm_bf<true><<<ggrid, blk, 0, stream>>>(hsb, Wqb, qb16, M, Dm, Dm);
  gemm_bf<true><<<ggrid, blk, 0, stream>>>(hsb, Wkb, kb16, M, Dm, Dm);
  gemm_bf<true><<<ggrid, blk, 0, stream>>>(hsb, Wvb, vb16, M, Dm, Dm);

  // flash attention v2
  attn_flash2<<<dim3(Lq / ATQ, Hh, Bb), dim3(512), 0, stream>>>(qb16, kb16, vb16, maskb, ctxb);

  // O projection -> fp32 out
  gemm_bf<false><<<ggrid, blk, 0, stream>>>(ctxb, Wob, out, M, Dm, Dm);
}

// Round 5
// 675.739 us; speedup vs baseline: 13.6526x; 1.0780x over previous
//
#include <hip/hip_runtime.h>
#include <math.h>
#include <stdint.h>

// Problem constants (match reference)
#define Bb 2
#define Lq 2048
#define Dm 2048
#define Hh 16
#define DH 128
#define DREL 64
#define KTOP 512   // 0.25 * L

#define NEG_INF (-__builtin_huge_valf())

typedef __attribute__((ext_vector_type(8))) short bf16x8;   // 8 bf16 (4 VGPRs)
typedef __attribute__((ext_vector_type(4))) float f32x4;

static __device__ __forceinline__ unsigned short f2bf(float f) {
  unsigned int u = __float_as_uint(f);
  u += 0x7fffu + ((u >> 16) & 1u);   // RNE
  return (unsigned short)(u >> 16);
}

// async global->LDS, 16B per lane; LDS dest = wave-uniform base + lane*16
static __device__ __forceinline__ void gload16(const void* g, void* lds) {
  __builtin_amdgcn_global_load_lds(
      (const __attribute__((address_space(1))) uint32_t*)(uintptr_t)g,
      (__attribute__((address_space(3))) uint32_t*)(uint32_t)(uintptr_t)lds,
      16, 0, 0);
}

// ---------------------------------------------------------------------------
// fp32 -> bf16 elementwise (n8 = n/8)
// ---------------------------------------------------------------------------
__global__ __launch_bounds__(256) void conv_bf16(const float* __restrict__ in,
                                                 unsigned short* __restrict__ out,
                                                 int n8) {
  const int i = blockIdx.x * 256 + threadIdx.x;
  if (i >= n8) return;
  const float4 f0 = ((const float4*)in)[2 * i];
  const float4 f1 = ((const float4*)in)[2 * i + 1];
  bf16x8 o;
  o[0] = (short)f2bf(f0.x); o[1] = (short)f2bf(f0.y);
  o[2] = (short)f2bf(f0.z); o[3] = (short)f2bf(f0.w);
  o[4] = (short)f2bf(f1.x); o[5] = (short)f2bf(f1.y);
  o[6] = (short)f2bf(f1.z); o[7] = (short)f2bf(f1.w);
  *(bf16x8*)(out + 8 * (size_t)i) = o;
}

// ---------------------------------------------------------------------------
// bf16 MFMA GEMM (m97 structure): C[M,N] = A[M,K] @ W[N,K]^T, fp32 accum.
// ---------------------------------------------------------------------------
template <bool BF16OUT>
__global__ __launch_bounds__(256) void gemm_bf(const unsigned short* __restrict__ A,
                                               const unsigned short* __restrict__ W,
                                               void* __restrict__ Cv,
                                               int M, int N, int Kd) {
  __shared__ unsigned short As[128][32];
  __shared__ unsigned short Bs[128][32];
  const int tid = threadIdx.x;
  const int w = tid >> 6;
  const int lane = tid & 63;
  const int l15 = lane & 15;
  const int quad = lane >> 4;
  const int wm = w >> 1, wn = w & 1;
  const int m0 = blockIdx.y * 128, n0 = blockIdx.x * 128;

  const int srow = lane >> 2;        // 0..15
  const int scol = (lane & 3) * 8;   // element col (8 bf16 = 16B)

  const unsigned short* aR0 = A + (size_t)(m0 + w * 32 + srow) * Kd + scol;
  const unsigned short* aR1 = aR0 + (size_t)16 * Kd;
  const unsigned short* bR0 = W + (size_t)(n0 + w * 32 + srow) * Kd + scol;
  const unsigned short* bR1 = bR0 + (size_t)16 * Kd;

  f32x4 acc[4][4];
#pragma unroll
  for (int i = 0; i < 4; ++i)
#pragma unroll
    for (int j = 0; j < 4; ++j) acc[i][j] = (f32x4){0.f, 0.f, 0.f, 0.f};

  for (int k0 = 0; k0 < Kd; k0 += 32) {
    gload16(aR0 + k0, &As[w * 32][0]);
    gload16(aR1 + k0, &As[w * 32 + 16][0]);
    gload16(bR0 + k0, &Bs[w * 32][0]);
    gload16(bR1 + k0, &Bs[w * 32 + 16][0]);
    __syncthreads();

    bf16x8 af[4], bfr[4];
#pragma unroll
    for (int im = 0; im < 4; ++im)
      af[im] = *(const bf16x8*)&As[wm * 64 + im * 16 + l15][quad * 8];
#pragma unroll
    for (int in = 0; in < 4; ++in)
      bfr[in] = *(const bf16x8*)&Bs[wn * 64 + in * 16 + l15][quad * 8];
#pragma unroll
    for (int im = 0; im < 4; ++im)
#pragma unroll
      for (int in = 0; in < 4; ++in)
        acc[im][in] = __builtin_amdgcn_mfma_f32_16x16x32_bf16(af[im], bfr[in], acc[im][in], 0, 0, 0);
    __syncthreads();
  }

#pragma unroll
  for (int im = 0; im < 4; ++im) {
#pragma unroll
    for (int in = 0; in < 4; ++in) {
      const int col = n0 + wn * 64 + in * 16 + l15;
#pragma unroll
      for (int r = 0; r < 4; ++r) {
        const int row = m0 + wm * 64 + im * 16 + quad * 4 + r;
        if (BF16OUT)
          ((unsigned short*)Cv)[(size_t)row * N + col] = f2bf(acc[im][in][r]);
        else
          ((float*)Cv)[(size_t)row * N + col] = acc[im][in][r];
      }
    }
  }
}

// ---------------------------------------------------------------------------
// Split-K fp32 rel projection: part[ks][128 rows][64 cols] over k-slice of 256.
// ---------------------------------------------------------------------------
#define RKS 8
__global__ __launch_bounds__(256) void relproj(const float* __restrict__ A,
                                               const float* __restrict__ W,
                                               float* __restrict__ part, int M) {
  __shared__ float As[16][128];
  __shared__ float Bs[16][64];
  const int ks = blockIdx.x;
  const int m0 = blockIdx.y * 128;
  const int tid = threadIdx.x;
  const int tx = tid & 15;   // col group (4 cols)
  const int ty = tid >> 4;   // row group (8 rows)
  const int lr = tid >> 1, lk = (tid & 1) * 8;
  const int wr = tid >> 2, wk = (tid & 3) * 4;

  float acc[8][4];
#pragma unroll
  for (int i = 0; i < 8; ++i)
#pragma unroll
    for (int j = 0; j < 4; ++j) acc[i][j] = 0.f;

  const int k00 = ks * (Dm / RKS);
  for (int k0 = k00; k0 < k00 + Dm / RKS; k0 += 16) {
    {
      const float* ap = A + (size_t)(m0 + lr) * Dm + k0 + lk;
      float4 a0 = *(const float4*)(ap);
      float4 a1 = *(const float4*)(ap + 4);
      As[lk + 0][lr] = a0.x; As[lk + 1][lr] = a0.y;
      As[lk + 2][lr] = a0.z; As[lk + 3][lr] = a0.w;
      As[lk + 4][lr] = a1.x; As[lk + 5][lr] = a1.y;
      As[lk + 6][lr] = a1.z; As[lk + 7][lr] = a1.w;
    }
    {
      const float* bp = W + (size_t)wr * Dm + k0 + wk;
      float4 b0 = *(const float4*)(bp);
      Bs[wk + 0][wr] = b0.x; Bs[wk + 1][wr] = b0.y;
      Bs[wk + 2][wr] = b0.z; Bs[wk + 3][wr] = b0.w;
    }
    __syncthreads();
#pragma unroll
    for (int kk = 0; kk < 16; ++kk) {
      float af[8], bf[4];
#pragma unroll
      for (int i = 0; i < 8; ++i) af[i] = As[kk][ty * 8 + i];
#pragma unroll
      for (int j = 0; j < 4; ++j) bf[j] = Bs[kk][tx * 4 + j];
#pragma unroll
      for (int i = 0; i < 8; ++i)
#pragma unroll
        for (int j = 0; j < 4; ++j) acc[i][j] += af[i] * bf[j];
    }
    __syncthreads();
  }

#pragma unroll
  for (int i = 0; i < 8; ++i) {
    float* pp = part + ((size_t)ks * M + m0 + ty * 8 + i) * DREL + tx * 4;
    *(float4*)pp = make_float4(acc[i][0], acc[i][1], acc[i][2], acc[i][3]);
  }
}

__global__ __launch_bounds__(256) void relreduce(const float* __restrict__ pq,
                                                 const float* __restrict__ pk,
                                                 float* __restrict__ qrel,
                                                 float* __restrict__ krel, int n4) {
  const int i = blockIdx.x * 256 + threadIdx.x;
  if (i >= n4) return;
  float4 sq = make_float4(0, 0, 0, 0), sk = sq;
  for (int s = 0; s < RKS; ++s) {
    float4 a = ((const float4*)pq)[(size_t)s * n4 + i];
    float4 b = ((const float4*)pk)[(size_t)s * n4 + i];
    sq.x += a.x; sq.y += a.y; sq.z += a.z; sq.w += a.w;
    sk.x += b.x; sk.y += b.y; sk.z += b.z; sk.w += b.w;
  }
  ((float4*)qrel)[i] = sq;
  ((float4*)krel)[i] = sk;
}

// ---------------------------------------------------------------------------
// Per-(b,q) rel-score + exact top-K -> bitmask.
// Radix-256 4-level histogram select (same fp32 total order as before, same
// kth semantics), ~12 barriers instead of ~128 and 4 key scans instead of 32.
// Mask emission via __ballot (one 64-bit word per wave iteration).
// ---------------------------------------------------------------------------
__global__ __launch_bounds__(256) void relmask_kernel(const float* __restrict__ qrel,
                                                      const float* __restrict__ krel,
                                                      uint32_t* __restrict__ mask) {
  const int bid = blockIdx.x;
  const int qi = bid % Lq;
  const int b = bid / Lq;
  const int tid = threadIdx.x;
  const int lane = tid & 63;

  __shared__ float qv[DREL];
  __shared__ uint32_t keys[Lq];
  __shared__ uint32_t hist[256];
  __shared__ uint32_t pref_s;
  __shared__ int rem_s;

  if (tid < DREL) qv[tid] = qrel[((size_t)(b * Lq + qi)) * DREL + tid];
  __syncthreads();

  const int n = qi + 1;

  // scores -> monotone u32 keys (fp32 total order), only j < n
  for (int j = tid; j < n; j += 256) {
    const float4* kp = (const float4*)(krel + ((size_t)(b * Lq + j)) * DREL);
    float acc = 0.0f;
#pragma unroll
    for (int t = 0; t < DREL / 4; ++t) {
      float4 k4 = kp[t];
      acc += qv[4 * t + 0] * k4.x + qv[4 * t + 1] * k4.y +
             qv[4 * t + 2] * k4.z + qv[4 * t + 3] * k4.w;
    }
    const float s = acc * 0.125f;  // DREL^-0.5
    uint32_t u = __float_as_uint(s);
    keys[j] = (u & 0x80000000u) ? ~u : (u | 0x80000000u);
  }
  __syncthreads();

  uint32_t kth = 0u;
  if (n > KTOP) {
    uint32_t pref = 0u;
    int rem = KTOP;
#pragma unroll
    for (int lvl = 0; lvl < 4; ++lvl) {
      const int shift = 24 - 8 * lvl;
      hist[tid] = 0u;
      __syncthreads();
      if (lvl == 0) {
        for (int j = tid; j < n; j += 256)
          atomicAdd(&hist[keys[j] >> 24], 1u);
      } else {
        const int hs = shift + 8;
        for (int j = tid; j < n; j += 256) {
          const uint32_t k = keys[j];
          if ((k >> hs) == pref) atomicAdd(&hist[(k >> shift) & 255u], 1u);
        }
      }
      __syncthreads();
      if (tid < 64) {  // wave 0: suffix-scan 256 bins, 4 bins/lane
        const uint32_t h0 = hist[4 * tid + 0];
        const uint32_t h1 = hist[4 * tid + 1];
        const uint32_t h2 = hist[4 * tid + 2];
        const uint32_t h3 = hist[4 * tid + 3];
        uint32_t T = h0 + h1 + h2 + h3;
#pragma unroll
        for (int d = 1; d < 64; d <<= 1) {
          const uint32_t v = (uint32_t)__shfl_down((int)T, d);
          if (tid + d < 64) T += v;
        }
        uint32_t Tn = (uint32_t)__shfl_down((int)T, 1);
        if (tid == 63) Tn = 0u;
        const uint32_t ur = (uint32_t)rem;
        if (T >= ur && Tn < ur) {  // exactly one lane
          int bsel;
          uint32_t above;
          if (Tn + h3 >= ur)                { bsel = 4 * tid + 3; above = Tn; }
          else if (Tn + h3 + h2 >= ur)      { bsel = 4 * tid + 2; above = Tn + h3; }
          else if (Tn + h3 + h2 + h1 >= ur) { bsel = 4 * tid + 1; above = Tn + h3 + h2; }
          else                              { bsel = 4 * tid + 0; above = Tn + h3 + h2 + h1; }
          pref_s = (pref << 8) | (uint32_t)bsel;
          rem_s = rem - (int)above;
        }
      }
      __syncthreads();
      pref = pref_s;
      rem = rem_s;
    }
    kth = pref;
  }

  // mask emission: each wave handles 64-key chunks via ballot
  uint32_t* mrow = mask + ((size_t)(b * Lq + qi)) * (Lq / 32);
  const int w = tid >> 6;
#pragma unroll
  for (int it = 0; it < 8; ++it) {
    const int c = w + 4 * it;        // chunk 0..31
    const int j = c * 64 + lane;     // < 2048 always
    const uint32_t k = keys[j];      // undefined for j>=n, gated below
    const bool ok = (j < n) && ((n <= KTOP) || (k >= kth) || (j == qi));
    const unsigned long long bal = __ballot(ok);
    if (lane == 0) {
      mrow[2 * c] = (uint32_t)bal;
      mrow[2 * c + 1] = (uint32_t)(bal >> 32);
    }
  }
}

// ---------------------------------------------------------------------------
// Flash attention v2: S^T formulation, no-max softmax (shift-invariant),
// P stays in registers. 512 thr = 8 waves, TQ=128, TK=32.
// ---------------------------------------------------------------------------
#define ATQ 128
__global__ __launch_bounds__(512) void attn_flash2(const unsigned short* __restrict__ qb,
                                                   const unsigned short* __restrict__ kb,
                                                   const unsigned short* __restrict__ vb,
                                                   const uint32_t* __restrict__ mask,
                                                   unsigned short* __restrict__ ctx) {
  __shared__ unsigned short Ks[32][136];  // [key][dim]+pad
  __shared__ unsigned short Vt[64][72];   // row=d>>1, col=(d&1)*32 + slot
  __shared__ uint32_t mw[ATQ];

  const int qt = (int)gridDim.x - 1 - (int)blockIdx.x;  // heavy blocks first
  const int h = blockIdx.y;
  const int b = blockIdx.z;
  const int tid = threadIdx.x;
  const int w = tid >> 6;          // wave 0..7
  const int lane = tid & 63;
  const int l15 = lane & 15;
  const int quad = lane >> 4;

  const int q0 = qt * ATQ;
  const float C = 0.08838834764831845f * 1.4426950408889634f;  // DH^-0.5 * log2(e)

  const int myq = q0 + w * 16 + l15;
  const unsigned short* qrow = qb + ((size_t)(b * Lq + myq)) * Dm + h * DH;
  bf16x8 bq[4];
#pragma unroll
  for (int kk = 0; kk < 4; ++kk) bq[kk] = *(const bf16x8*)(qrow + kk * 32 + quad * 8);

  f32x4 O[8];  // O^T: O[f][r] = ctx[q=l15][f*16 + quad*4 + r]
#pragma unroll
  for (int f = 0; f < 8; ++f) O[f] = (f32x4){0.f, 0.f, 0.f, 0.f};
  float l_lane = 0.f;

  const int nt = (q0 + ATQ) / 32;

  const int skey = (tid & 255) >> 3;   // 0..31
  const int scg = tid & 7;             // 0..7 -> dims scg*16..+16
  const int tv = tid - 256;
  const int vkp = tv & 15;             // key pair v
  const int vdg = tv >> 4;             // 0..15 -> dims vdg*8..+8
  const int dwc = ((vkp >> 1) & 3) * 4 + (vkp >> 3) * 2 + (vkp & 1);

  for (int kt = 0; kt < nt; ++kt) {
    const int kbase = kt * 32;
    if (tid < 256) {
      const unsigned short* kr = kb + ((size_t)(b * Lq + kbase + skey)) * Dm + h * DH + scg * 16;
      bf16x8 lo = *(const bf16x8*)(kr);
      bf16x8 hi = *(const bf16x8*)(kr + 8);
      *(bf16x8*)&Ks[skey][scg * 16] = lo;
      *(bf16x8*)&Ks[skey][scg * 16 + 8] = hi;
    } else {
      const unsigned short* va = vb + ((size_t)(b * Lq + kbase + 2 * vkp)) * Dm + h * DH + vdg * 8;
      bf16x8 a8 = *(const bf16x8*)(va);
      bf16x8 b8 = *(const bf16x8*)(va + Dm);
#pragma unroll
      for (int i = 0; i < 8; ++i) {
        const int d = vdg * 8 + i;
        uint32_t pk = (uint32_t)(unsigned short)a8[i] | ((uint32_t)(unsigned short)b8[i] << 16);
        ((uint32_t*)&Vt[d >> 1][0])[(d & 1) * 16 + dwc] = pk;
      }
    }
    if (tid < ATQ) mw[tid] = mask[((size_t)(b * Lq + q0 + tid)) * (Lq / 32) + kt];
    __syncthreads();

    // S^T = K Q^T
    f32x4 acc0 = (f32x4){0.f, 0.f, 0.f, 0.f};
    f32x4 acc1 = acc0;
#pragma unroll
    for (int kk = 0; kk < 4; ++kk) {
      bf16x8 a0 = *(const bf16x8*)&Ks[l15][kk * 32 + quad * 8];
      bf16x8 a1 = *(const bf16x8*)&Ks[16 + l15][kk * 32 + quad * 8];
      acc0 = __builtin_amdgcn_mfma_f32_16x16x32_bf16(a0, bq[kk], acc0, 0, 0, 0);
      acc1 = __builtin_amdgcn_mfma_f32_16x16x32_bf16(a1, bq[kk], acc1, 0, 0, 0);
    }

    // softmax numerator (no max shift), build P^T B-frag in registers
    const uint32_t mword = mw[w * 16 + l15];
    bf16x8 bp;
    float ps = 0.f;
#pragma unroll
    for (int r = 0; r < 4; ++r) {
      const float p0 = ((mword >> (quad * 4 + r)) & 1u) ? __builtin_amdgcn_exp2f(acc0[r] * C) : 0.f;
      const float p1 = ((mword >> (16 + quad * 4 + r)) & 1u) ? __builtin_amdgcn_exp2f(acc1[r] * C) : 0.f;
      ps += p0 + p1;
      bp[r] = (short)f2bf(p0);
      bp[4 + r] = (short)f2bf(p1);
    }
    l_lane += ps;

    // O^T += V^T P^T
#pragma unroll
    for (int f = 0; f < 8; ++f) {
      const int d = f * 16 + l15;
      bf16x8 av = *(const bf16x8*)&Vt[d >> 1][(d & 1) * 32 + quad * 8];
      O[f] = __builtin_amdgcn_mfma_f32_16x16x32_bf16(av, bp, O[f], 0, 0, 0);
    }
    __syncthreads();
  }

  l_lane += __shfl_xor(l_lane, 16);
  l_lane += __shfl_xor(l_lane, 32);
  const float rl = 1.0f / l_lane;

  unsigned short* orow = ctx + ((size_t)(b * Lq + q0 + w * 16 + l15)) * Dm + h * DH;
#pragma unroll
  for (int f = 0; f < 8; ++f) {
    ushort4 o4;
    o4.x = f2bf(O[f][0] * rl);
    o4.y = f2bf(O[f][1] * rl);
    o4.z = f2bf(O[f][2] * rl);
    o4.w = f2bf(O[f][3] * rl);
    *(ushort4*)(orow + f * 16 + quad * 4) = o4;
  }
}

// ---------------------------------------------------------------------------
extern "C" void kernel_launch(void* const* d_in, const int* in_sizes, int n_in,
                              void* d_out, int out_size, void* d_ws, size_t ws_size,
                              hipStream_t stream) {
  const float* hs  = (const float*)d_in[0];
  const float* rel = (const float*)d_in[1];
  const float* Wqr = (const float*)d_in[2];
  const float* Wkr = (const float*)d_in[3];
  const float* Wq  = (const float*)d_in[4];
  const float* Wk  = (const float*)d_in[5];
  const float* Wv  = (const float*)d_in[6];
  const float* Wo  = (const float*)d_in[7];
  float* out = (float*)d_out;

  const int M = Bb * Lq;   // 4096
  const int ND = Dm * Dm;
  char* ws = (char*)d_ws;
  size_t off = 0;
  float* qrel = (float*)(ws + off); off += (size_t)M * DREL * 4;
  float* krel = (float*)(ws + off); off += (size_t)M * DREL * 4;
  float* partq = (float*)(ws + off); off += (size_t)RKS * M * DREL * 4;
  float* partk = (float*)(ws + off); off += (size_t)RKS * M * DREL * 4;
  uint32_t* maskb = (uint32_t*)(ws + off); off += (size_t)M * (Lq / 32) * 4;
  unsigned short* hsb  = (unsigned short*)(ws + off); off += (size_t)M * Dm * 2;
  unsigned short* qb16 = (unsigned short*)(ws + off); off += (size_t)M * Dm * 2;
  unsigned short* kb16 = (unsigned short*)(ws + off); off += (size_t)M * Dm * 2;
  unsigned short* vb16 = (unsigned short*)(ws + off); off += (size_t)M * Dm * 2;
  unsigned short* ctxb = (unsigned short*)(ws + off); off += (size_t)M * Dm * 2;
  unsigned short* Wqb  = (unsigned short*)(ws + off); off += (size_t)ND * 2;
  unsigned short* Wkb  = (unsigned short*)(ws + off); off += (size_t)ND * 2;
  unsigned short* Wvb  = (unsigned short*)(ws + off); off += (size_t)ND * 2;
  unsigned short* Wob  = (unsigned short*)(ws + off); off += (size_t)ND * 2;

  const dim3 blk(256);
  const int hsN8 = M * Dm / 8;
  const int wN8  = ND / 8;

  // rel projections (fp32-exact, split-K deterministic) + top-K mask
  relproj<<<dim3(RKS, M / 128), blk, 0, stream>>>(rel, Wqr, partq, M);
  relproj<<<dim3(RKS, M / 128), blk, 0, stream>>>(rel, Wkr, partk, M);
  relreduce<<<(M * DREL / 4 + 255) / 256, blk, 0, stream>>>(partq, partk, qrel, krel, M * DREL / 4);
  relmask_kernel<<<M, blk, 0, stream>>>(qrel, krel, maskb);

  // bf16 conversions
  conv_bf16<<<(hsN8 + 255) / 256, blk, 0, stream>>>(hs, hsb, hsN8);
  conv_bf16<<<(wN8 + 255) / 256, blk, 0, stream>>>(Wq, Wqb, wN8);
  conv_bf16<<<(wN8 + 255) / 256, blk, 0, stream>>>(Wk, Wkb, wN8);
  conv_bf16<<<(wN8 + 255) / 256, blk, 0, stream>>>(Wv, Wvb, wN8);
  conv_bf16<<<(wN8 + 255) / 256, blk, 0, stream>>>(Wo, Wob, wN8);

  // QKV projections (bf16 MFMA)
  const dim3 ggrid(Dm / 128, M / 128);
  gemm_bf<true><<<ggrid, blk, 0, stream>>>(hsb, Wqb, qb16, M, Dm, Dm);
  gemm_bf<true><<<ggrid, blk, 0, stream>>>(hsb, Wkb, kb16, M, Dm, Dm);
  gemm_bf<true><<<ggrid, blk, 0, stream>>>(hsb, Wvb, vb16, M, Dm, Dm);

  // flash attention v2
  attn_flash2<<<dim3(Lq / ATQ, Hh, Bb), dim3(512), 0, stream>>>(qb16, kb16, vb16, maskb, ctxb);

  // O projection -> fp32 out
  gemm_bf<false><<<ggrid, blk, 0, stream>>>(ctxb, Wob, out, M, Dm, Dm);
}

// Round 6
// 595.617 us; speedup vs baseline: 15.4891x; 1.1345x over previous
//
#include <hip/hip_runtime.h>
#include <math.h>
#include <stdint.h>

// Problem constants (match reference)
#define Bb 2
#define Lq 2048
#define Dm 2048
#define Hh 16
#define DH 128
#define DREL 64
#define KTOP 512   // 0.25 * L

#define NEG_INF (-__builtin_huge_valf())

typedef __attribute__((ext_vector_type(8))) short bf16x8;   // 8 bf16 (4 VGPRs)
typedef __attribute__((ext_vector_type(4))) float f32x4;

static __device__ __forceinline__ unsigned short f2bf(float f) {
  unsigned int u = __float_as_uint(f);
  u += 0x7fffu + ((u >> 16) & 1u);   // RNE
  return (unsigned short)(u >> 16);
}

// async global->LDS, 16B per lane; LDS dest = wave-uniform base + lane*16
static __device__ __forceinline__ void gload16(const void* g, void* lds) {
  __builtin_amdgcn_global_load_lds(
      (const __attribute__((address_space(1))) uint32_t*)(uintptr_t)g,
      (__attribute__((address_space(3))) uint32_t*)(uint32_t)(uintptr_t)lds,
      16, 0, 0);
}

// ---------------------------------------------------------------------------
// fp32 -> bf16 elementwise (n8 = n/8)
// ---------------------------------------------------------------------------
__global__ __launch_bounds__(256) void conv_bf16(const float* __restrict__ in,
                                                 unsigned short* __restrict__ out,
                                                 int n8) {
  const int i = blockIdx.x * 256 + threadIdx.x;
  if (i >= n8) return;
  const float4 f0 = ((const float4*)in)[2 * i];
  const float4 f1 = ((const float4*)in)[2 * i + 1];
  bf16x8 o;
  o[0] = (short)f2bf(f0.x); o[1] = (short)f2bf(f0.y);
  o[2] = (short)f2bf(f0.z); o[3] = (short)f2bf(f0.w);
  o[4] = (short)f2bf(f1.x); o[5] = (short)f2bf(f1.y);
  o[6] = (short)f2bf(f1.z); o[7] = (short)f2bf(f1.w);
  *(bf16x8*)(out + 8 * (size_t)i) = o;
}

// ---------------------------------------------------------------------------
// bf16 MFMA GEMM (m97 structure): C[M,N] = A[M,K] @ W[N,K]^T, fp32 accum.
// ---------------------------------------------------------------------------
template <bool BF16OUT>
__global__ __launch_bounds__(256) void gemm_bf(const unsigned short* __restrict__ A,
                                               const unsigned short* __restrict__ W,
                                               void* __restrict__ Cv,
                                               int M, int N, int Kd) {
  __shared__ unsigned short As[128][32];
  __shared__ unsigned short Bs[128][32];
  const int tid = threadIdx.x;
  const int w = tid >> 6;
  const int lane = tid & 63;
  const int l15 = lane & 15;
  const int quad = lane >> 4;
  const int wm = w >> 1, wn = w & 1;
  const int m0 = blockIdx.y * 128, n0 = blockIdx.x * 128;

  const int srow = lane >> 2;        // 0..15
  const int scol = (lane & 3) * 8;   // element col (8 bf16 = 16B)

  const unsigned short* aR0 = A + (size_t)(m0 + w * 32 + srow) * Kd + scol;
  const unsigned short* aR1 = aR0 + (size_t)16 * Kd;
  const unsigned short* bR0 = W + (size_t)(n0 + w * 32 + srow) * Kd + scol;
  const unsigned short* bR1 = bR0 + (size_t)16 * Kd;

  f32x4 acc[4][4];
#pragma unroll
  for (int i = 0; i < 4; ++i)
#pragma unroll
    for (int j = 0; j < 4; ++j) acc[i][j] = (f32x4){0.f, 0.f, 0.f, 0.f};

  for (int k0 = 0; k0 < Kd; k0 += 32) {
    gload16(aR0 + k0, &As[w * 32][0]);
    gload16(aR1 + k0, &As[w * 32 + 16][0]);
    gload16(bR0 + k0, &Bs[w * 32][0]);
    gload16(bR1 + k0, &Bs[w * 32 + 16][0]);
    __syncthreads();

    bf16x8 af[4], bfr[4];
#pragma unroll
    for (int im = 0; im < 4; ++im)
      af[im] = *(const bf16x8*)&As[wm * 64 + im * 16 + l15][quad * 8];
#pragma unroll
    for (int in = 0; in < 4; ++in)
      bfr[in] = *(const bf16x8*)&Bs[wn * 64 + in * 16 + l15][quad * 8];
#pragma unroll
    for (int im = 0; im < 4; ++im)
#pragma unroll
      for (int in = 0; in < 4; ++in)
        acc[im][in] = __builtin_amdgcn_mfma_f32_16x16x32_bf16(af[im], bfr[in], acc[im][in], 0, 0, 0);
    __syncthreads();
  }

#pragma unroll
  for (int im = 0; im < 4; ++im) {
#pragma unroll
    for (int in = 0; in < 4; ++in) {
      const int col = n0 + wn * 64 + in * 16 + l15;
#pragma unroll
      for (int r = 0; r < 4; ++r) {
        const int row = m0 + wm * 64 + im * 16 + quad * 4 + r;
        if (BF16OUT)
          ((unsigned short*)Cv)[(size_t)row * N + col] = f2bf(acc[im][in][r]);
        else
          ((float*)Cv)[(size_t)row * N + col] = acc[im][in][r];
      }
    }
  }
}

// ---------------------------------------------------------------------------
// Split-K fp32 rel projection: part[ks][128 rows][64 cols] over k-slice of 256.
// ---------------------------------------------------------------------------
#define RKS 8
__global__ __launch_bounds__(256) void relproj(const float* __restrict__ A,
                                               const float* __restrict__ W,
                                               float* __restrict__ part, int M) {
  __shared__ float As[16][128];
  __shared__ float Bs[16][64];
  const int ks = blockIdx.x;
  const int m0 = blockIdx.y * 128;
  const int tid = threadIdx.x;
  const int tx = tid & 15;   // col group (4 cols)
  const int ty = tid >> 4;   // row group (8 rows)
  const int lr = tid >> 1, lk = (tid & 1) * 8;
  const int wr = tid >> 2, wk = (tid & 3) * 4;

  float acc[8][4];
#pragma unroll
  for (int i = 0; i < 8; ++i)
#pragma unroll
    for (int j = 0; j < 4; ++j) acc[i][j] = 0.f;

  const int k00 = ks * (Dm / RKS);
  for (int k0 = k00; k0 < k00 + Dm / RKS; k0 += 16) {
    {
      const float* ap = A + (size_t)(m0 + lr) * Dm + k0 + lk;
      float4 a0 = *(const float4*)(ap);
      float4 a1 = *(const float4*)(ap + 4);
      As[lk + 0][lr] = a0.x; As[lk + 1][lr] = a0.y;
      As[lk + 2][lr] = a0.z; As[lk + 3][lr] = a0.w;
      As[lk + 4][lr] = a1.x; As[lk + 5][lr] = a1.y;
      As[lk + 6][lr] = a1.z; As[lk + 7][lr] = a1.w;
    }
    {
      const float* bp = W + (size_t)wr * Dm + k0 + wk;
      float4 b0 = *(const float4*)(bp);
      Bs[wk + 0][wr] = b0.x; Bs[wk + 1][wr] = b0.y;
      Bs[wk + 2][wr] = b0.z; Bs[wk + 3][wr] = b0.w;
    }
    __syncthreads();
#pragma unroll
    for (int kk = 0; kk < 16; ++kk) {
      float af[8], bf[4];
#pragma unroll
      for (int i = 0; i < 8; ++i) af[i] = As[kk][ty * 8 + i];
#pragma unroll
      for (int j = 0; j < 4; ++j) bf[j] = Bs[kk][tx * 4 + j];
#pragma unroll
      for (int i = 0; i < 8; ++i)
#pragma unroll
        for (int j = 0; j < 4; ++j) acc[i][j] += af[i] * bf[j];
    }
    __syncthreads();
  }

#pragma unroll
  for (int i = 0; i < 8; ++i) {
    float* pp = part + ((size_t)ks * M + m0 + ty * 8 + i) * DREL + tx * 4;
    *(float4*)pp = make_float4(acc[i][0], acc[i][1], acc[i][2], acc[i][3]);
  }
}

__global__ __launch_bounds__(256) void relreduce(const float* __restrict__ pq,
                                                 const float* __restrict__ pk,
                                                 float* __restrict__ qrel,
                                                 float* __restrict__ krel, int n4) {
  const int i = blockIdx.x * 256 + threadIdx.x;
  if (i >= n4) return;
  float4 sq = make_float4(0, 0, 0, 0), sk = sq;
  for (int s = 0; s < RKS; ++s) {
    float4 a = ((const float4*)pq)[(size_t)s * n4 + i];
    float4 b = ((const float4*)pk)[(size_t)s * n4 + i];
    sq.x += a.x; sq.y += a.y; sq.z += a.z; sq.w += a.w;
    sk.x += b.x; sk.y += b.y; sk.z += b.z; sk.w += b.w;
  }
  ((float4*)qrel)[i] = sq;
  ((float4*)krel)[i] = sk;
}

// ---------------------------------------------------------------------------
// Dense triangular rel-score GEMM: S[b][q][j] = (qrel[b,q,:]·krel[b,j,:])*DREL^-0.5
// 128x128 tile per block; upper-triangle tile blocks exit immediately.
// ---------------------------------------------------------------------------
__global__ __launch_bounds__(256) void relscore(const float* __restrict__ qrel,
                                                const float* __restrict__ krel,
                                                float* __restrict__ S) {
  const int jt = blockIdx.x, qt = blockIdx.y, b = blockIdx.z;
  if (jt > qt) return;
  __shared__ float As[16][128];
  __shared__ float Bs[16][128];
  const int tid = threadIdx.x;
  const int q0 = qt * 128, j0 = jt * 128;
  const int tx = tid & 15, ty = tid >> 4;
  const int lr = tid >> 1, lk = (tid & 1) * 8;
  const float* Ab = qrel + (size_t)b * Lq * DREL;
  const float* Kb = krel + (size_t)b * Lq * DREL;

  float acc[8][8];
#pragma unroll
  for (int i = 0; i < 8; ++i)
#pragma unroll
    for (int j = 0; j < 8; ++j) acc[i][j] = 0.f;

  for (int k0 = 0; k0 < DREL; k0 += 16) {
    {
      const float* ap = Ab + (size_t)(q0 + lr) * DREL + k0 + lk;
      float4 a0 = *(const float4*)(ap);
      float4 a1 = *(const float4*)(ap + 4);
      As[lk + 0][lr] = a0.x; As[lk + 1][lr] = a0.y;
      As[lk + 2][lr] = a0.z; As[lk + 3][lr] = a0.w;
      As[lk + 4][lr] = a1.x; As[lk + 5][lr] = a1.y;
      As[lk + 6][lr] = a1.z; As[lk + 7][lr] = a1.w;
    }
    {
      const float* bp = Kb + (size_t)(j0 + lr) * DREL + k0 + lk;
      float4 b0 = *(const float4*)(bp);
      float4 b1 = *(const float4*)(bp + 4);
      Bs[lk + 0][lr] = b0.x; Bs[lk + 1][lr] = b0.y;
      Bs[lk + 2][lr] = b0.z; Bs[lk + 3][lr] = b0.w;
      Bs[lk + 4][lr] = b1.x; Bs[lk + 5][lr] = b1.y;
      Bs[lk + 6][lr] = b1.z; Bs[lk + 7][lr] = b1.w;
    }
    __syncthreads();
#pragma unroll
    for (int kk = 0; kk < 16; ++kk) {
      float af[8], bf[8];
#pragma unroll
      for (int i = 0; i < 8; ++i) af[i] = As[kk][ty * 8 + i];
#pragma unroll
      for (int j = 0; j < 8; ++j) bf[j] = Bs[kk][tx * 8 + j];
#pragma unroll
      for (int i = 0; i < 8; ++i)
#pragma unroll
        for (int j = 0; j < 8; ++j) acc[i][j] += af[i] * bf[j];
    }
    __syncthreads();
  }

  const float sc = 0.125f;  // DREL^-0.5
#pragma unroll
  for (int i = 0; i < 8; ++i) {
    float* cp = S + ((size_t)b * Lq + q0 + ty * 8 + i) * Lq + j0 + tx * 8;
    ((float4*)cp)[0] = make_float4(acc[i][0] * sc, acc[i][1] * sc, acc[i][2] * sc, acc[i][3] * sc);
    ((float4*)cp)[1] = make_float4(acc[i][4] * sc, acc[i][5] * sc, acc[i][6] * sc, acc[i][7] * sc);
  }
}

// ---------------------------------------------------------------------------
// Wave-per-row exact top-K select + mask emission, all in registers.
// 32 keys/lane; 32-level bitwise radix select (same fp32 total order and
// tie semantics as before); emission via __ballot. No LDS/barriers/atomics.
// ---------------------------------------------------------------------------
__global__ __launch_bounds__(256) void relselect(const float* __restrict__ S,
                                                 uint32_t* __restrict__ mask) {
  const int w = threadIdx.x >> 6;
  const int lane = threadIdx.x & 63;
  const int ridx = blockIdx.x * 4 + w;      // = b*Lq + qi
  const int qi = ridx & (Lq - 1);
  const int n = qi + 1;
  const float* srow = S + (size_t)ridx * Lq;

  uint32_t keys[32];
#pragma unroll
  for (int t = 0; t < 32; ++t) {
    const int j = t * 64 + lane;
    const uint32_t u = __float_as_uint(srow[j]);
    const uint32_t k = (u & 0x80000000u) ? ~u : (u | 0x80000000u);
    keys[t] = (j < n) ? k : 0u;   // 0 never matches any candidate prefix
  }

  uint32_t kth = 0u;
  if (n > KTOP) {
    uint32_t pref = 0u;
    int rem = KTOP;
    for (int bit = 31; bit >= 0; --bit) {
      const uint32_t cand = pref | (1u << bit);
      const uint32_t lim = 1u << bit;
      int c = 0;
#pragma unroll
      for (int t = 0; t < 32; ++t) c += ((keys[t] ^ cand) < lim) ? 1 : 0;
      c += __shfl_xor(c, 1);
      c += __shfl_xor(c, 2);
      c += __shfl_xor(c, 4);
      c += __shfl_xor(c, 8);
      c += __shfl_xor(c, 16);
      c += __shfl_xor(c, 32);
      if (c >= rem) pref = cand;
      else rem -= c;
    }
    kth = pref;
  }

  uint32_t* mrow = mask + (size_t)ridx * (Lq / 32);
#pragma unroll
  for (int t = 0; t < 32; ++t) {
    const int j = t * 64 + lane;
    const bool ok = (j < n) && (keys[t] >= kth || j == qi);  // kth=0 -> causal-only
    const unsigned long long bal = __ballot(ok);
    if (lane == 0) {
      mrow[2 * t] = (uint32_t)bal;
      mrow[2 * t + 1] = (uint32_t)(bal >> 32);
    }
  }
}

// ---------------------------------------------------------------------------
// Flash attention v2: S^T formulation, no-max softmax (shift-invariant),
// P stays in registers. 512 thr = 8 waves, TQ=128, TK=32.
// ---------------------------------------------------------------------------
#define ATQ 128
__global__ __launch_bounds__(512) void attn_flash2(const unsigned short* __restrict__ qb,
                                                   const unsigned short* __restrict__ kb,
                                                   const unsigned short* __restrict__ vb,
                                                   const uint32_t* __restrict__ mask,
                                                   unsigned short* __restrict__ ctx) {
  __shared__ unsigned short Ks[32][136];  // [key][dim]+pad
  __shared__ unsigned short Vt[64][72];   // row=d>>1, col=(d&1)*32 + slot
  __shared__ uint32_t mw[ATQ];

  const int qt = (int)gridDim.x - 1 - (int)blockIdx.x;  // heavy blocks first
  const int h = blockIdx.y;
  const int b = blockIdx.z;
  const int tid = threadIdx.x;
  const int w = tid >> 6;          // wave 0..7
  const int lane = tid & 63;
  const int l15 = lane & 15;
  const int quad = lane >> 4;

  const int q0 = qt * ATQ;
  const float C = 0.08838834764831845f * 1.4426950408889634f;  // DH^-0.5 * log2(e)

  const int myq = q0 + w * 16 + l15;
  const unsigned short* qrow = qb + ((size_t)(b * Lq + myq)) * Dm + h * DH;
  bf16x8 bq[4];
#pragma unroll
  for (int kk = 0; kk < 4; ++kk) bq[kk] = *(const bf16x8*)(qrow + kk * 32 + quad * 8);

  f32x4 O[8];  // O^T: O[f][r] = ctx[q=l15][f*16 + quad*4 + r]
#pragma unroll
  for (int f = 0; f < 8; ++f) O[f] = (f32x4){0.f, 0.f, 0.f, 0.f};
  float l_lane = 0.f;

  const int nt = (q0 + ATQ) / 32;

  const int skey = (tid & 255) >> 3;   // 0..31
  const int scg = tid & 7;             // 0..7 -> dims scg*16..+16
  const int tv = tid - 256;
  const int vkp = tv & 15;             // key pair v
  const int vdg = tv >> 4;             // 0..15 -> dims vdg*8..+8
  const int dwc = ((vkp >> 1) & 3) * 4 + (vkp >> 3) * 2 + (vkp & 1);

  for (int kt = 0; kt < nt; ++kt) {
    const int kbase = kt * 32;
    if (tid < 256) {
      const unsigned short* kr = kb + ((size_t)(b * Lq + kbase + skey)) * Dm + h * DH + scg * 16;
      bf16x8 lo = *(const bf16x8*)(kr);
      bf16x8 hi = *(const bf16x8*)(kr + 8);
      *(bf16x8*)&Ks[skey][scg * 16] = lo;
      *(bf16x8*)&Ks[skey][scg * 16 + 8] = hi;
    } else {
      const unsigned short* va = vb + ((size_t)(b * Lq + kbase + 2 * vkp)) * Dm + h * DH + vdg * 8;
      bf16x8 a8 = *(const bf16x8*)(va);
      bf16x8 b8 = *(const bf16x8*)(va + Dm);
#pragma unroll
      for (int i = 0; i < 8; ++i) {
        const int d = vdg * 8 + i;
        uint32_t pk = (uint32_t)(unsigned short)a8[i] | ((uint32_t)(unsigned short)b8[i] << 16);
        ((uint32_t*)&Vt[d >> 1][0])[(d & 1) * 16 + dwc] = pk;
      }
    }
    if (tid < ATQ) mw[tid] = mask[((size_t)(b * Lq + q0 + tid)) * (Lq / 32) + kt];
    __syncthreads();

    // S^T = K Q^T
    f32x4 acc0 = (f32x4){0.f, 0.f, 0.f, 0.f};
    f32x4 acc1 = acc0;
#pragma unroll
    for (int kk = 0; kk < 4; ++kk) {
      bf16x8 a0 = *(const bf16x8*)&Ks[l15][kk * 32 + quad * 8];
      bf16x8 a1 = *(const bf16x8*)&Ks[16 + l15][kk * 32 + quad * 8];
      acc0 = __builtin_amdgcn_mfma_f32_16x16x32_bf16(a0, bq[kk], acc0, 0, 0, 0);
      acc1 = __builtin_amdgcn_mfma_f32_16x16x32_bf16(a1, bq[kk], acc1, 0, 0, 0);
    }

    // softmax numerator (no max shift), build P^T B-frag in registers
    const uint32_t mword = mw[w * 16 + l15];
    bf16x8 bp;
    float ps = 0.f;
#pragma unroll
    for (int r = 0; r < 4; ++r) {
      const float p0 = ((mword >> (quad * 4 + r)) & 1u) ? __builtin_amdgcn_exp2f(acc0[r] * C) : 0.f;
      const float p1 = ((mword >> (16 + quad * 4 + r)) & 1u) ? __builtin_amdgcn_exp2f(acc1[r] * C) : 0.f;
      ps += p0 + p1;
      bp[r] = (short)f2bf(p0);
      bp[4 + r] = (short)f2bf(p1);
    }
    l_lane += ps;

    // O^T += V^T P^T
#pragma unroll
    for (int f = 0; f < 8; ++f) {
      const int d = f * 16 + l15;
      bf16x8 av = *(const bf16x8*)&Vt[d >> 1][(d & 1) * 32 + quad * 8];
      O[f] = __builtin_amdgcn_mfma_f32_16x16x32_bf16(av, bp, O[f], 0, 0, 0);
    }
    __syncthreads();
  }

  l_lane += __shfl_xor(l_lane, 16);
  l_lane += __shfl_xor(l_lane, 32);
  const float rl = 1.0f / l_lane;

  unsigned short* orow = ctx + ((size_t)(b * Lq + q0 + w * 16 + l15)) * Dm + h * DH;
#pragma unroll
  for (int f = 0; f < 8; ++f) {
    ushort4 o4;
    o4.x = f2bf(O[f][0] * rl);
    o4.y = f2bf(O[f][1] * rl);
    o4.z = f2bf(O[f][2] * rl);
    o4.w = f2bf(O[f][3] * rl);
    *(ushort4*)(orow + f * 16 + quad * 4) = o4;
  }
}

// ---------------------------------------------------------------------------
extern "C" void kernel_launch(void* const* d_in, const int* in_sizes, int n_in,
                              void* d_out, int out_size, void* d_ws, size_t ws_size,
                              hipStream_t stream) {
  const float* hs  = (const float*)d_in[0];
  const float* rel = (const float*)d_in[1];
  const float* Wqr = (const float*)d_in[2];
  const float* Wkr = (const float*)d_in[3];
  const float* Wq  = (const float*)d_in[4];
  const float* Wk  = (const float*)d_in[5];
  const float* Wv  = (const float*)d_in[6];
  const float* Wo  = (const float*)d_in[7];
  float* out = (float*)d_out;

  const int M = Bb * Lq;   // 4096
  const int ND = Dm * Dm;
  char* ws = (char*)d_ws;
  size_t off = 0;
  float* qrel = (float*)(ws + off); off += (size_t)M * DREL * 4;
  float* krel = (float*)(ws + off); off += (size_t)M * DREL * 4;
  uint32_t* maskb = (uint32_t*)(ws + off); off += (size_t)M * (Lq / 32) * 4;
  float* partq = (float*)(ws + off); off += (size_t)RKS * M * DREL * 4;
  float* partk = (float*)(ws + off); off += (size_t)RKS * M * DREL * 4;
  // bf16 staging region; Sbuf (B*L*L fp32 = 33.5 MB) is ALIASED onto its head:
  // Sbuf is consumed by relselect before any bf16 buffer is written (in-order stream).
  float* Sbuf = (float*)(ws + off);
  unsigned short* hsb  = (unsigned short*)(ws + off); off += (size_t)M * Dm * 2;
  unsigned short* qb16 = (unsigned short*)(ws + off); off += (size_t)M * Dm * 2;
  unsigned short* kb16 = (unsigned short*)(ws + off); off += (size_t)M * Dm * 2;
  unsigned short* vb16 = (unsigned short*)(ws + off); off += (size_t)M * Dm * 2;
  unsigned short* ctxb = (unsigned short*)(ws + off); off += (size_t)M * Dm * 2;
  unsigned short* Wqb  = (unsigned short*)(ws + off); off += (size_t)ND * 2;
  unsigned short* Wkb  = (unsigned short*)(ws + off); off += (size_t)ND * 2;
  unsigned short* Wvb  = (unsigned short*)(ws + off); off += (size_t)ND * 2;
  unsigned short* Wob  = (unsigned short*)(ws + off); off += (size_t)ND * 2;

  const dim3 blk(256);
  const int hsN8 = M * Dm / 8;
  const int wN8  = ND / 8;

  // rel pipeline: fp32-exact projections -> dense triangular scores -> wave select
  relproj<<<dim3(RKS, M / 128), blk, 0, stream>>>(rel, Wqr, partq, M);
  relproj<<<dim3(RKS, M / 128), blk, 0, stream>>>(rel, Wkr, partk, M);
  relreduce<<<(M * DREL / 4 + 255) / 256, blk, 0, stream>>>(partq, partk, qrel, krel, M * DREL / 4);
  relscore<<<dim3(Lq / 128, Lq / 128, Bb), blk, 0, stream>>>(qrel, krel, Sbuf);
  relselect<<<M / 4, blk, 0, stream>>>(Sbuf, maskb);

  // bf16 conversions (overwrite Sbuf region only after relselect has consumed it)
  conv_bf16<<<(hsN8 + 255) / 256, blk, 0, stream>>>(hs, hsb, hsN8);
  conv_bf16<<<(wN8 + 255) / 256, blk, 0, stream>>>(Wq, Wqb, wN8);
  conv_bf16<<<(wN8 + 255) / 256, blk, 0, stream>>>(Wk, Wkb, wN8);
  conv_bf16<<<(wN8 + 255) / 256, blk, 0, stream>>>(Wv, Wvb, wN8);
  conv_bf16<<<(wN8 + 255) / 256, blk, 0, stream>>>(Wo, Wob, wN8);

  // QKV projections (bf16 MFMA)
  const dim3 ggrid(Dm / 128, M / 128);
  gemm_bf<true><<<ggrid, blk, 0, stream>>>(hsb, Wqb, qb16, M, Dm, Dm);
  gemm_bf<true><<<ggrid, blk, 0, stream>>>(hsb, Wkb, kb16, M, Dm, Dm);
  gemm_bf<true><<<ggrid, blk, 0, stream>>>(hsb, Wvb, vb16, M, Dm, Dm);

  // flash attention v2
  attn_flash2<<<dim3(Lq / ATQ, Hh, Bb), dim3(512), 0, stream>>>(qb16, kb16, vb16, maskb, ctxb);

  // O projection -> fp32 out
  gemm_bf<false><<<ggrid, blk, 0, stream>>>(ctxb, Wob, out, M, Dm, Dm);
}